// Round 3
// baseline (6809.872 us; speedup 1.0000x reference)
//
#include <hip/hip_runtime.h>
#include <hip/hip_bf16.h>

typedef __hip_bfloat16 bf16;

__device__ __forceinline__ float b2f(bf16 v) { return __bfloat162float(v); }
__device__ __forceinline__ bf16  f2b(float v) { return __float2bfloat16(v); }

// ---------------------------------------------------------------------------
// Static device arena: converted inputs + weights + ping-pong scratch.
// BSS allocation at module load -> independent of ws_size, graph-capture safe.
// Layout (bf16 elements):
//   [0)            imgs      12,441,600   (8*3*720*720)
//   [12441600)     crops24    3,538,944   (2048*3*24*24)
//   [15980544)     crops48    3,538,944   (512*3*48*48)
//   [19519488)     weights      600,000   (actual ~495,850; offsets from in_sizes)
//   [20119488)     A         10,500,000   (max user: PNet pool1 10,310,480)
//   [30619488)     B         16,500,000   (max user: PNet conv2 16,313,472)
// ---------------------------------------------------------------------------
#define OFF_IMGS 0
#define OFF_C24  12441600
#define OFF_C48  15980544
#define OFF_WTS  19519488
#define OFF_A    20119488
#define OFF_B    30619488
#define ARENA_N  47119488L

__device__ bf16 g_arena[ARENA_N];
__device__ int  g_isf32;

// ---------------------------------------------------------------------------
// Dtype detection: bf16 N(0,1) data has exponent field <= ~0x81 (|v|<8).
// fp32 data misread as u16 halves has random exponent bits in the odd
// (mantissa-low) halves -> exp >= 0x8D (|v|>=2^14) appears w.p. ~0.45/elem.
// ---------------------------------------------------------------------------
__global__ void detect_kern(const void* imgs)
{
    if (threadIdx.x != 0) return;
    const unsigned short* u = (const unsigned short*)imgs;
    int f32 = 0;
    for (int i = 0; i < 256; ++i) {
        int e = (u[i] >> 7) & 0xFF;
        if (e >= 0x8D) f32 = 1;
    }
    g_isf32 = f32;
}

// Convert one large array into the arena (flag-branched, wave-uniform).
__global__ void convert_kern(const void* __restrict__ src, int dst_off, int n)
{
    int i = blockIdx.x * blockDim.x + threadIdx.x;
    if (i >= n) return;
    float v = g_isf32 ? ((const float*)src)[i] : b2f(((const bf16*)src)[i]);
    g_arena[(long)dst_off + i] = f2b(v);
}

// Convert all 50 weight/bias/alpha arrays in one dispatch (blockIdx.y = array).
struct CvtEnt { const void* src; int dst_off; int n; };
struct CvtTab { CvtEnt e[50]; };
__global__ void convert_many_kern(CvtTab tab)
{
    CvtEnt ent = tab.e[blockIdx.y];
    int i = blockIdx.x * blockDim.x + threadIdx.x;
    if (i >= ent.n) return;
    float v = g_isf32 ? ((const float*)ent.src)[i] : b2f(((const bf16*)ent.src)[i]);
    g_arena[(long)ent.dst_off + i] = f2b(v);
}

// Flag-branched output store (element offsets identical for both dtypes).
__device__ __forceinline__ void stout(void* base, long idx, float v, int f32)
{
    if (f32) ((float*)base)[idx] = v;
    else     ((bf16*)base)[idx] = f2b(v);
}

// ---------------------------------------------------------------------------
// Fused: conv3x3 (CIN=3) + bias + PReLU + maxpool(k,s, ceil_mode).
// One thread per pooled output element. OOB pool taps skipped.
// ---------------------------------------------------------------------------
__global__ void conv1_pool_kern(int in_off, int w_off, int b_off, int a_off, int out_off,
                                int CO, int H, int W, int CH, int CW,
                                int OH, int OW, int k, int s, int total)
{
    int tid = blockIdx.x * blockDim.x + threadIdx.x;
    if (tid >= total) return;
    const bf16* in  = g_arena + in_off;
    const bf16* w   = g_arena + w_off;
    int x = tid % OW;
    int t = tid / OW;
    int y = t % OH; t /= OH;
    int o = t % CO;
    int n = t / CO;

    const bf16* ip = in + (long)n * 3 * H * W;
    const bf16* wp = w + (long)o * 27;
    float b = b2f(g_arena[b_off + o]);
    float a = b2f(g_arena[a_off + o]);
    float m = -1e30f;
    for (int ky = 0; ky < k; ++ky) {
        int cy = y * s + ky;
        if (cy >= CH) break;
        for (int kx = 0; kx < k; ++kx) {
            int cx = x * s + kx;
            if (cx >= CW) break;
            float acc = b;
            #pragma unroll
            for (int c = 0; c < 3; ++c) {
                const bf16* ic = ip + (long)c * H * W + (long)cy * W + cx;
                const bf16* wc = wp + c * 9;
                #pragma unroll
                for (int iy = 0; iy < 3; ++iy)
                    #pragma unroll
                    for (int ix = 0; ix < 3; ++ix)
                        acc += b2f(ic[iy * W + ix]) * b2f(wc[iy * 3 + ix]);
            }
            acc = acc > 0.f ? acc : acc * a;
            m = fmaxf(m, acc);
        }
    }
    g_arena[(long)out_off + tid] = f2b(m);
}

// ---------------------------------------------------------------------------
// Direct conv (VALID, stride 1) + bias + PReLU.
// ---------------------------------------------------------------------------
template<int CIN, int KH, int KW>
__global__ void conv_prelu_kern(int in_off, int w_off, int b_off, int a_off, int out_off,
                                int CO, int H, int W, int OH, int OW, int total)
{
    int tid = blockIdx.x * blockDim.x + threadIdx.x;
    if (tid >= total) return;
    const bf16* in = g_arena + in_off;
    const bf16* w  = g_arena + w_off;
    int x = tid % OW;
    int t = tid / OW;
    int y = t % OH; t /= OH;
    int o = t % CO;
    int n = t / CO;

    const bf16* ip = in + ((long)n * CIN) * H * W + (long)y * W + x;
    const bf16* wp = w + (long)o * (CIN * KH * KW);
    float acc = b2f(g_arena[b_off + o]);
    for (int c = 0; c < CIN; ++c) {
        const bf16* ic = ip + (long)c * H * W;
        const bf16* wc = wp + c * (KH * KW);
        #pragma unroll
        for (int ky = 0; ky < KH; ++ky)
            #pragma unroll
            for (int kx = 0; kx < KW; ++kx)
                acc += b2f(ic[ky * W + kx]) * b2f(wc[ky * KW + kx]);
    }
    float a = b2f(g_arena[a_off + o]);
    acc = acc > 0.f ? acc : acc * a;
    g_arena[(long)out_off + tid] = f2b(acc);
}

// ---------------------------------------------------------------------------
// MaxPool2d, ceil_mode (OOB taps skipped).
// ---------------------------------------------------------------------------
__global__ void maxpool_kern(int in_off, int out_off,
                             int H, int W, int OH, int OW, int k, int s, int total)
{
    int tid = blockIdx.x * blockDim.x + threadIdx.x;
    if (tid >= total) return;
    int x = tid % OW;
    int t = tid / OW;
    int y = t % OH;
    int nc = t / OH;
    const bf16* ip = g_arena + in_off + (long)nc * H * W;
    int sy = y * s, sx = x * s;
    float m = -1e30f;
    for (int ky = 0; ky < k; ++ky) {
        int iy = sy + ky;
        if (iy >= H) break;
        for (int kx = 0; kx < k; ++kx) {
            int ix = sx + kx;
            if (ix >= W) break;
            m = fmaxf(m, b2f(ip[iy * W + ix]));
        }
    }
    g_arena[(long)out_off + tid] = f2b(m);
}

// ---------------------------------------------------------------------------
// PNet conv3 (16->32) + PReLU + both 1x1 heads + softmax, fully fused.
// conv3 weights transposed to LDS fp32 [t=c*9+ky*3+kx][o].
// ---------------------------------------------------------------------------
__global__ void pnet_conv3_head_kern(int conv2_off,
                                     int w3o, int b3o, int a3o,
                                     int w41o, int b41o, int w42o, int b42o,
                                     void* dout, int total)   // total = 8*355*355
{
    __shared__ float w3f[144 * 32];
    __shared__ float b3f[32], a3f[32];
    __shared__ float w41f[64], w42f[128];
    __shared__ float b41f[2], b42f[4];

    for (int i = threadIdx.x; i < 4608; i += blockDim.x) {
        int o = i / 144, t = i % 144;
        w3f[t * 32 + o] = b2f(g_arena[w3o + i]);
    }
    for (int i = threadIdx.x; i < 32; i += blockDim.x) {
        b3f[i] = b2f(g_arena[b3o + i]);
        a3f[i] = b2f(g_arena[a3o + i]);
    }
    for (int i = threadIdx.x; i < 64; i += blockDim.x) w41f[i] = b2f(g_arena[w41o + i]);
    for (int i = threadIdx.x; i < 128; i += blockDim.x) w42f[i] = b2f(g_arena[w42o + i]);
    if (threadIdx.x < 2) b41f[threadIdx.x] = b2f(g_arena[b41o + threadIdx.x]);
    if (threadIdx.x < 4) b42f[threadIdx.x] = b2f(g_arena[b42o + threadIdx.x]);
    __syncthreads();

    int tid = blockIdx.x * blockDim.x + threadIdx.x;
    if (tid >= total) return;
    int f32 = g_isf32;
    const int OW = 355, HW = 355 * 355, IW = 357;
    int x = tid % OW;
    int t = tid / OW;
    int y = t % 355;
    int n = t / 355;

    float c3[32];
    #pragma unroll
    for (int o = 0; o < 32; ++o) c3[o] = b3f[o];

    const bf16* base = g_arena + conv2_off + ((long)n * 16) * IW * IW + (long)y * IW + x;
    for (int c = 0; c < 16; ++c) {
        const bf16* ic = base + (long)c * IW * IW;
        #pragma unroll
        for (int ky = 0; ky < 3; ++ky) {
            #pragma unroll
            for (int kx = 0; kx < 3; ++kx) {
                float v = b2f(ic[ky * IW + kx]);
                const float* wr = &w3f[(c * 9 + ky * 3 + kx) * 32];
                #pragma unroll
                for (int o = 0; o < 32; ++o)
                    c3[o] += v * wr[o];
            }
        }
    }
    float l0 = b41f[0], l1 = b41f[1];
    float r0 = b42f[0], r1 = b42f[1], r2 = b42f[2], r3 = b42f[3];
    #pragma unroll
    for (int o = 0; o < 32; ++o) {
        float v = c3[o];
        v = v > 0.f ? v : v * a3f[o];
        l0 += v * w41f[o];
        l1 += v * w41f[32 + o];
        r0 += v * w42f[o];
        r1 += v * w42f[32 + o];
        r2 += v * w42f[64 + o];
        r3 += v * w42f[96 + o];
    }
    float mx = fmaxf(l0, l1);
    float e0 = __expf(l0 - mx), e1 = __expf(l1 - mx);
    float inv = 1.f / (e0 + e1);
    long pix = (long)y * OW + x;
    // p_reg at element 0, p_prob at element 4032800 of d_out
    stout(dout, 4032800 + ((long)n * 2 + 0) * HW + pix, e0 * inv, f32);
    stout(dout, 4032800 + ((long)n * 2 + 1) * HW + pix, e1 * inv, f32);
    stout(dout, ((long)n * 4 + 0) * HW + pix, r0, f32);
    stout(dout, ((long)n * 4 + 1) * HW + pix, r1, f32);
    stout(dout, ((long)n * 4 + 2) * HW + pix, r2, f32);
    stout(dout, ((long)n * 4 + 3) * HW + pix, r3, f32);
}

// ---------------------------------------------------------------------------
// Flatten with torch permute(0,3,2,1).view(N,-1): out[n][w*H*C + h*C + c]
// ---------------------------------------------------------------------------
__global__ void flatten_kern(int in_off, int out_off, int C, int H, int W, int total)
{
    int tid = blockIdx.x * blockDim.x + threadIdx.x;
    if (tid >= total) return;
    int CHW = C * H * W;
    int n = tid / CHW;
    int k = tid % CHW;
    int w = k / (H * C);
    int r = k % (H * C);
    int h = r / C;
    int c = r % C;
    g_arena[(long)out_off + tid] = g_arena[in_off + (((long)n * C + c) * H + h) * W + w];
}

// ---------------------------------------------------------------------------
// Dense + bias + PReLU.
// ---------------------------------------------------------------------------
__global__ void dense_prelu_kern(int in_off, int w_off, int b_off, int a_off, int out_off,
                                 int K, int J, int total)
{
    int tid = blockIdx.x * blockDim.x + threadIdx.x;
    if (tid >= total) return;
    int j = tid % J;
    int n = tid / J;
    const bf16* ip = g_arena + in_off + (long)n * K;
    const bf16* wp = g_arena + w_off + (long)j * K;
    float acc = b2f(g_arena[b_off + j]);
    for (int k = 0; k < K; ++k)
        acc += b2f(ip[k]) * b2f(wp[k]);
    float a = b2f(g_arena[a_off + j]);
    acc = acc > 0.f ? acc : acc * a;
    g_arena[(long)out_off + tid] = f2b(acc);
}

// ---------------------------------------------------------------------------
// R/O-Net heads: one thread per sample; outputs go to d_out element offsets.
// ---------------------------------------------------------------------------
__global__ void heads_kern(int fc_off, int wSo, int bSo, int w1o, int b1o,
                           int w2o, int b2o, void* dout,
                           long outS_off, long out1_off, long out2_off,
                           int N, int K, int J1, int J2)
{
    int n = blockIdx.x * blockDim.x + threadIdx.x;
    if (n >= N) return;
    int f32 = g_isf32;
    const bf16* f = g_arena + fc_off + (long)n * K;
    float l0 = b2f(g_arena[bSo + 0]), l1 = b2f(g_arena[bSo + 1]);
    const bf16* wS = g_arena + wSo;
    for (int k = 0; k < K; ++k) {
        float v = b2f(f[k]);
        l0 += v * b2f(wS[k]);
        l1 += v * b2f(wS[K + k]);
    }
    float m = fmaxf(l0, l1);
    float e0 = __expf(l0 - m), e1 = __expf(l1 - m);
    float inv = 1.f / (e0 + e1);
    stout(dout, outS_off + (long)n * 2 + 0, e0 * inv, f32);
    stout(dout, outS_off + (long)n * 2 + 1, e1 * inv, f32);
    for (int j = 0; j < J1; ++j) {
        float acc = b2f(g_arena[b1o + j]);
        const bf16* wp = g_arena + w1o + (long)j * K;
        for (int k = 0; k < K; ++k)
            acc += b2f(f[k]) * b2f(wp[k]);
        stout(dout, out1_off + (long)n * J1 + j, acc, f32);
    }
    if (J2 > 0) {
        for (int j = 0; j < J2; ++j) {
            float acc = b2f(g_arena[b2o + j]);
            const bf16* wp = g_arena + w2o + (long)j * K;
            for (int k = 0; k < K; ++k)
                acc += b2f(f[k]) * b2f(wp[k]);
            stout(dout, out2_off + (long)n * J2 + j, acc, f32);
        }
    }
}

static inline dim3 g1(int total) { return dim3((unsigned)((total + 255) / 256)); }

extern "C" void kernel_launch(void* const* d_in, const int* in_sizes, int n_in,
                              void* d_out, int out_size, void* d_ws, size_t ws_size,
                              hipStream_t stream)
{
    // Weight arena offsets computed from in_sizes (inputs 3..52).
    int woff[53];
    int acc = OFF_WTS;
    int mx = 0;
    for (int i = 3; i < 53; ++i) { woff[i] = acc; acc += in_sizes[i]; if (in_sizes[i] > mx) mx = in_sizes[i]; }

    // ---- dtype detect + convert all inputs into the arena ----
    detect_kern<<<1, 64, 0, stream>>>(d_in[0]);
    convert_kern<<<g1(12441600), 256, 0, stream>>>(d_in[0], OFF_IMGS, 12441600);
    convert_kern<<<g1(3538944), 256, 0, stream>>>(d_in[1], OFF_C24, 3538944);
    convert_kern<<<g1(3538944), 256, 0, stream>>>(d_in[2], OFF_C48, 3538944);
    CvtTab tab;
    for (int i = 3; i < 53; ++i) tab.e[i - 3] = CvtEnt{ d_in[i], woff[i], in_sizes[i] };
    convert_many_kern<<<dim3((unsigned)((mx + 255) / 256), 50), 256, 0, stream>>>(tab);

    // d_out element offsets (return order):
    // p_reg 0 | p_prob 4032800 | r_b 6049200 | r_a 6057392 | o_b 6061488 | o_c 6063536 | o_a 6068656

    // ================= PNet =================
    conv1_pool_kern<<<g1(10310480), 256, 0, stream>>>(OFF_IMGS, woff[3], woff[4], woff[5], OFF_A,
        10, 720, 720, 718, 718, 359, 359, 2, 2, 10310480);
    conv_prelu_kern<10,3,3><<<g1(16313472), 256, 0, stream>>>(OFF_A, woff[6], woff[7], woff[8], OFF_B,
        16, 359, 359, 357, 357, 16313472);
    pnet_conv3_head_kern<<<g1(1008200), 256, 0, stream>>>(OFF_B,
        woff[9], woff[10], woff[11], woff[12], woff[13], woff[14], woff[15],
        d_out, 1008200);

    // ================= RNet =================
    conv1_pool_kern<<<g1(6938624), 256, 0, stream>>>(OFF_C24, woff[16], woff[17], woff[18], OFF_A,
        28, 24, 24, 22, 22, 11, 11, 3, 2, 6938624);
    conv_prelu_kern<28,3,3><<<g1(7962624), 256, 0, stream>>>(OFF_A, woff[19], woff[20], woff[21], OFF_B,
        48, 11, 11, 9, 9, 7962624);
    maxpool_kern<<<g1(1572864), 256, 0, stream>>>(OFF_B, OFF_A, 9, 9, 4, 4, 3, 2, 1572864);
    conv_prelu_kern<48,2,2><<<g1(1179648), 256, 0, stream>>>(OFF_A, woff[22], woff[23], woff[24], OFF_B,
        64, 4, 4, 3, 3, 1179648);
    flatten_kern<<<g1(1179648), 256, 0, stream>>>(OFF_B, OFF_A, 64, 3, 3, 1179648);
    dense_prelu_kern<<<g1(262144), 256, 0, stream>>>(OFF_A, woff[25], woff[26], woff[27], OFF_B,
        576, 128, 262144);
    heads_kern<<<g1(2048), 256, 0, stream>>>(OFF_B, woff[28], woff[29], woff[30], woff[31],
        0, 0, d_out, 6057392L, 6049200L, 0L, 2048, 128, 4, 0);

    // ================= ONet =================
    conv1_pool_kern<<<g1(8667136), 256, 0, stream>>>(OFF_C48, woff[32], woff[33], woff[34], OFF_A,
        32, 48, 48, 46, 46, 23, 23, 3, 2, 8667136);
    conv_prelu_kern<32,3,3><<<g1(14450688), 256, 0, stream>>>(OFF_A, woff[35], woff[36], woff[37], OFF_B,
        64, 23, 23, 21, 21, 14450688);
    maxpool_kern<<<g1(3276800), 256, 0, stream>>>(OFF_B, OFF_A, 21, 21, 10, 10, 3, 2, 3276800);
    conv_prelu_kern<64,3,3><<<g1(2097152), 256, 0, stream>>>(OFF_A, woff[38], woff[39], woff[40], OFF_B,
        64, 10, 10, 8, 8, 2097152);
    maxpool_kern<<<g1(524288), 256, 0, stream>>>(OFF_B, OFF_A, 8, 8, 4, 4, 2, 2, 524288);
    conv_prelu_kern<64,2,2><<<g1(589824), 256, 0, stream>>>(OFF_A, woff[41], woff[42], woff[43], OFF_B,
        128, 4, 4, 3, 3, 589824);
    flatten_kern<<<g1(589824), 256, 0, stream>>>(OFF_B, OFF_A, 128, 3, 3, 589824);
    dense_prelu_kern<<<g1(131072), 256, 0, stream>>>(OFF_A, woff[44], woff[45], woff[46], OFF_B,
        1152, 256, 131072);
    heads_kern<<<g1(512), 256, 0, stream>>>(OFF_B, woff[47], woff[48], woff[49], woff[50],
        woff[51], woff[52], d_out, 6068656L, 6061488L, 6063536L, 512, 256, 4, 10);
}

// Round 4
// 2849.946 us; speedup vs baseline: 2.3895x; 2.3895x over previous
//
#include <hip/hip_runtime.h>
#include <hip/hip_bf16.h>

typedef __hip_bfloat16 bf16;
typedef unsigned short u16;
typedef unsigned int u32;

__device__ __forceinline__ float b2f(bf16 v) { return __bfloat162float(v); }
__device__ __forceinline__ bf16  f2b(float v) { return __float2bfloat16(v); }
__device__ __forceinline__ float us2f(u16 u) { return __uint_as_float((u32)u << 16); }
__device__ __forceinline__ float ulo(u32 u)  { return __uint_as_float(u << 16); }
__device__ __forceinline__ float uhi(u32 u)  { return __uint_as_float(u & 0xFFFF0000u); }

// ---------------------------------------------------------------------------
// Static device arena (BSS, ~143 MB): converted inputs + weights + scratch.
//   [0)          imgs      12,441,600
//   [12441600)   crops24    3,538,944
//   [15980544)   crops48    3,538,944
//   [19519488)   weights      600,000
//   [20119488)   A         34,700,000   (max: ONet conv1 out 34,668,544)
//   [54819488)   B         16,500,000   (max: PNet conv2 out 16,313,472)
// ---------------------------------------------------------------------------
#define OFF_IMGS 0
#define OFF_C24  12441600
#define OFF_C48  15980544
#define OFF_WTS  19519488
#define OFF_A    20119488
#define OFF_B    54819488
#define ARENA_N  71319488L

__device__ bf16 g_arena[ARENA_N];
__device__ int  g_isf32;

// ---------------------------------------------------------------------------
// Dtype detection (bf16 N(0,1) never has exponent >= 0x8D; fp32 misread does).
// ---------------------------------------------------------------------------
__global__ void detect_kern(const void* imgs)
{
    if (threadIdx.x != 0) return;
    const u16* u = (const u16*)imgs;
    int f32 = 0;
    for (int i = 0; i < 256; ++i) {
        int e = (u[i] >> 7) & 0xFF;
        if (e >= 0x8D) f32 = 1;
    }
    g_isf32 = f32;
}

__global__ void convert_kern(const void* __restrict__ src, int dst_off, int n)
{
    int i = blockIdx.x * blockDim.x + threadIdx.x;
    if (i >= n) return;
    float v = g_isf32 ? ((const float*)src)[i] : b2f(((const bf16*)src)[i]);
    g_arena[(long)dst_off + i] = f2b(v);
}

struct CvtEnt { const void* src; int dst_off; int n; };
struct CvtTab { CvtEnt e[50]; };
__global__ void convert_many_kern(CvtTab tab)
{
    CvtEnt ent = tab.e[blockIdx.y];
    int i = blockIdx.x * blockDim.x + threadIdx.x;
    if (i >= ent.n) return;
    float v = g_isf32 ? ((const float*)ent.src)[i] : b2f(((const bf16*)ent.src)[i]);
    g_arena[(long)ent.dst_off + i] = f2b(v);
}

__device__ __forceinline__ void stout(void* base, long idx, float v, int f32)
{
    if (f32) ((float*)base)[idx] = v;
    else     ((bf16*)base)[idx] = f2b(v);
}

// ---------------------------------------------------------------------------
// Generic LDS-resident conv for crop nets (whole image fits in LDS).
// Block = (image n, pixel-chunk, o-chunk). 256 threads = 32 px-lanes x 8
// o-groups. Each thread: R pixels x OPT outputs in registers. Weights staged
// transposed [k][OBLK] bf16; inner loop reads R inputs + OPT/2 packed words.
// ---------------------------------------------------------------------------
template<int CIN,int KH,int KW,int H,int W,int OH,int OW,int CO,int OBLK,int R>
__launch_bounds__(256)
__global__ void conv_a_kern(int in_off, int w_off, int b_off, int a_off, int out_off)
{
    constexpr int KTOT = CIN * KH * KW;
    constexpr int INCNT = CIN * H * W;      // even for all instantiations
    constexpr int OPT = OBLK / 8;
    constexpr int NPX = OH * OW;
    __shared__ __align__(16) u16 in_s[INCNT];
    __shared__ __align__(16) u16 w_s[KTOT * OBLK];

    int n = blockIdx.x, pxc = blockIdx.y, oc = blockIdx.z;
    const u16* ga = (const u16*)g_arena;

    const u32* src = (const u32*)(ga + in_off + (long)n * INCNT);
    u32* dst = (u32*)in_s;
    for (int i = threadIdx.x; i < INCNT / 2; i += 256) dst[i] = src[i];
    for (int i = threadIdx.x; i < KTOT * OBLK; i += 256) {
        int o_l = i % OBLK, k = i / OBLK;
        int o = oc * OBLK + o_l;
        w_s[i] = (o < CO) ? ga[w_off + (long)o * KTOT + k] : (u16)0;
    }
    __syncthreads();

    int lane = threadIdx.x & 31, og = threadIdx.x >> 5;
    int pixoff[R], pxg[R];
    bool vld[R];
    #pragma unroll
    for (int r = 0; r < R; ++r) {
        int px = pxc * (32 * R) + lane + r * 32;
        vld[r] = px < NPX;
        int p = vld[r] ? px : 0;
        pxg[r] = p;
        pixoff[r] = (p / OW) * W + (p % OW);
    }
    float acc[R][OPT];
    #pragma unroll
    for (int r = 0; r < R; ++r)
        #pragma unroll
        for (int j = 0; j < OPT; ++j) acc[r][j] = 0.f;

    const u32* wu = (const u32*)w_s;
    for (int c = 0; c < CIN; ++c) {
        #pragma unroll
        for (int ky = 0; ky < KH; ++ky) {
            #pragma unroll
            for (int kx = 0; kx < KW; ++kx) {
                int k = (c * KH + ky) * KW + kx;
                int ub = c * (H * W) + ky * W + kx;
                float a[R];
                #pragma unroll
                for (int r = 0; r < R; ++r) a[r] = us2f(in_s[ub + pixoff[r]]);
                int wb = (k * OBLK + og * OPT) >> 1;
                float wv[OPT];
                #pragma unroll
                for (int jj = 0; jj < OPT / 2; ++jj) {
                    u32 u = wu[wb + jj];
                    wv[2 * jj] = ulo(u); wv[2 * jj + 1] = uhi(u);
                }
                #pragma unroll
                for (int r = 0; r < R; ++r)
                    #pragma unroll
                    for (int j = 0; j < OPT; ++j)
                        acc[r][j] += a[r] * wv[j];
            }
        }
    }
    #pragma unroll
    for (int j = 0; j < OPT; ++j) {
        int o = oc * OBLK + og * OPT + j;
        if (o < CO) {
            float b = us2f(ga[b_off + o]);
            float al = us2f(ga[a_off + o]);
            #pragma unroll
            for (int r = 0; r < R; ++r) if (vld[r]) {
                float v = acc[r][j] + b;
                v = v > 0.f ? v : v * al;
                g_arena[(long)out_off + ((long)n * CO + o) * NPX + pxg[r]] = f2b(v);
            }
        }
    }
}

// ---------------------------------------------------------------------------
// PNet conv1 (3->10, 720^2 -> 718^2) + PReLU + maxpool 2x2 s2 -> 359^2.
// Block = (n, pool-tile 16x16). Patch 34x34x3 in LDS. Thread = pool pixel,
// 2x2 conv pix x 10 o in registers.
// ---------------------------------------------------------------------------
__launch_bounds__(256)
__global__ void pnet_c1p_kern(int w_off, int b_off, int a_off, int out_off)
{
    __shared__ u16 patch[3 * 34 * 34];                 // 3468
    __shared__ __align__(16) u16 w_s[27 * 16];         // padded o to 16
    int n = blockIdx.x, pty = blockIdx.y, ptx = blockIdx.z;
    int cy0 = pty * 32, cx0 = ptx * 32;
    const u16* ga = (const u16*)g_arena;

    for (int i = threadIdx.x; i < 3468; i += 256) {
        int c = i / 1156, rem = i % 1156, py = rem / 34, pxx = rem % 34;
        int iy = cy0 + py, ix = cx0 + pxx;
        u16 v = 0;
        if (iy < 720 && ix < 720)
            v = ga[OFF_IMGS + ((long)(n * 3 + c) * 720 + iy) * 720 + ix];
        patch[i] = v;
    }
    for (int i = threadIdx.x; i < 27 * 16; i += 256) {
        int o = i % 16, k = i / 16;
        w_s[i] = (o < 10) ? ga[w_off + o * 27 + k] : (u16)0;
    }
    __syncthreads();

    int px = threadIdx.x % 16, py = threadIdx.x / 16;
    float acc[2][2][10];
    #pragma unroll
    for (int a = 0; a < 2; ++a)
        #pragma unroll
        for (int b = 0; b < 2; ++b)
            #pragma unroll
            for (int o = 0; o < 10; ++o) acc[a][b][o] = 0.f;

    const uint4* wq = (const uint4*)w_s;
    for (int c = 0; c < 3; ++c) {
        #pragma unroll
        for (int ky = 0; ky < 3; ++ky) {
            #pragma unroll
            for (int kx = 0; kx < 3; ++kx) {
                int k = (c * 3 + ky) * 3 + kx;
                float a[2][2];
                #pragma unroll
                for (int dy = 0; dy < 2; ++dy)
                    #pragma unroll
                    for (int dx = 0; dx < 2; ++dx)
                        a[dy][dx] = us2f(patch[c * 1156 + (2 * py + dy + ky) * 34 + (2 * px + dx + kx)]);
                uint4 q0 = wq[k * 2], q1 = wq[k * 2 + 1];
                float wv[10];
                wv[0] = ulo(q0.x); wv[1] = uhi(q0.x); wv[2] = ulo(q0.y); wv[3] = uhi(q0.y);
                wv[4] = ulo(q0.z); wv[5] = uhi(q0.z); wv[6] = ulo(q0.w); wv[7] = uhi(q0.w);
                wv[8] = ulo(q1.x); wv[9] = uhi(q1.x);
                #pragma unroll
                for (int o = 0; o < 10; ++o)
                    #pragma unroll
                    for (int dy = 0; dy < 2; ++dy)
                        #pragma unroll
                        for (int dx = 0; dx < 2; ++dx)
                            acc[dy][dx][o] += a[dy][dx] * wv[o];
            }
        }
    }
    int pgy = pty * 16 + py, pgx = ptx * 16 + px;
    if (pgy < 359 && pgx < 359) {
        #pragma unroll
        for (int o = 0; o < 10; ++o) {
            float b = us2f(ga[b_off + o]);
            float al = us2f(ga[a_off + o]);
            float m = -1e30f;
            #pragma unroll
            for (int dy = 0; dy < 2; ++dy)
                #pragma unroll
                for (int dx = 0; dx < 2; ++dx) {
                    float v = acc[dy][dx][o] + b;
                    v = v > 0.f ? v : v * al;
                    m = fmaxf(m, v);
                }
            g_arena[(long)out_off + ((long)(n * 10 + o) * 359 + pgy) * 359 + pgx] = f2b(m);
        }
    }
}

// ---------------------------------------------------------------------------
// PNet conv2 (10->16, 359^2 -> 357^2). Block = (n, tile 32x32). Patch
// 34x34x10 LDS. Thread: 4 rows x 16 o.
// ---------------------------------------------------------------------------
__launch_bounds__(256)
__global__ void pnet_c2_kern(int in_off, int w_off, int b_off, int a_off, int out_off)
{
    __shared__ u16 patch[10 * 34 * 34];                // 11560
    __shared__ __align__(16) u16 w_s[90 * 16];         // 1440
    int n = blockIdx.x, ty = blockIdx.y, tx = blockIdx.z;
    int y0 = ty * 32, x0 = tx * 32;
    const u16* ga = (const u16*)g_arena;

    for (int i = threadIdx.x; i < 11560; i += 256) {
        int c = i / 1156, rem = i % 1156, py = rem / 34, pxx = rem % 34;
        int iy = y0 + py, ix = x0 + pxx;
        u16 v = 0;
        if (iy < 359 && ix < 359)
            v = ga[in_off + ((long)(n * 10 + c) * 359 + iy) * 359 + ix];
        patch[i] = v;
    }
    for (int i = threadIdx.x; i < 1440; i += 256) {
        int o = i % 16, k = i / 16;
        w_s[i] = ga[w_off + o * 90 + k];
    }
    __syncthreads();

    int x = threadIdx.x % 32, yg = threadIdx.x / 32;
    float acc[4][16];
    #pragma unroll
    for (int r = 0; r < 4; ++r)
        #pragma unroll
        for (int o = 0; o < 16; ++o) acc[r][o] = 0.f;

    const uint4* wq = (const uint4*)w_s;
    for (int c = 0; c < 10; ++c) {
        #pragma unroll
        for (int ky = 0; ky < 3; ++ky) {
            #pragma unroll
            for (int kx = 0; kx < 3; ++kx) {
                int k = (c * 3 + ky) * 3 + kx;
                float a[4];
                #pragma unroll
                for (int r = 0; r < 4; ++r)
                    a[r] = us2f(patch[c * 1156 + (yg + 8 * r + ky) * 34 + (x + kx)]);
                uint4 q0 = wq[k * 2], q1 = wq[k * 2 + 1];
                float wv[16];
                wv[0]=ulo(q0.x); wv[1]=uhi(q0.x); wv[2]=ulo(q0.y); wv[3]=uhi(q0.y);
                wv[4]=ulo(q0.z); wv[5]=uhi(q0.z); wv[6]=ulo(q0.w); wv[7]=uhi(q0.w);
                wv[8]=ulo(q1.x); wv[9]=uhi(q1.x); wv[10]=ulo(q1.y); wv[11]=uhi(q1.y);
                wv[12]=ulo(q1.z); wv[13]=uhi(q1.z); wv[14]=ulo(q1.w); wv[15]=uhi(q1.w);
                #pragma unroll
                for (int r = 0; r < 4; ++r)
                    #pragma unroll
                    for (int o = 0; o < 16; ++o)
                        acc[r][o] += a[r] * wv[o];
            }
        }
    }
    #pragma unroll
    for (int o = 0; o < 16; ++o) {
        float b = us2f(ga[b_off + o]);
        float al = us2f(ga[a_off + o]);
        #pragma unroll
        for (int r = 0; r < 4; ++r) {
            int gy = y0 + yg + 8 * r, gx = x0 + x;
            if (gy < 357 && gx < 357) {
                float v = acc[r][o] + b;
                v = v > 0.f ? v : v * al;
                g_arena[(long)out_off + ((long)(n * 16 + o) * 357 + gy) * 357 + gx] = f2b(v);
            }
        }
    }
}

// ---------------------------------------------------------------------------
// PNet conv3 (16->32, 357^2 -> 355^2) + PReLU + 1x1 heads + softmax, fused.
// Block = (n, 8-row band, 32-col tile) = 256 out px, all 32 o in-block.
// conv3 via 64 px-lanes x 4 o-groups x (R=4, OPT=8); head via LDS tile.
// ---------------------------------------------------------------------------
__launch_bounds__(256)
__global__ void pnet_c3h_kern(int in_off, int w3o, int b3o, int a3o,
                              int w41o, int b41o, int w42o, int b42o, void* dout)
{
    __shared__ u16 patch[16 * 10 * 34];                // 5440
    __shared__ __align__(16) u16 w3s[144 * 32];        // 4608
    __shared__ float c3s[256 * 33];                    // padded stride 33
    __shared__ float b3f[32], a3f[32], w41f[64], w42f[128], b41f[2], b42f[4];

    int n = blockIdx.x, by = blockIdx.y, tx = blockIdx.z;
    int gy0 = by * 8, gx0 = tx * 32;
    const u16* ga = (const u16*)g_arena;

    for (int i = threadIdx.x; i < 5440; i += 256) {
        int c = i / 340, rem = i % 340, py = rem / 34, pxx = rem % 34;
        int iy = gy0 + py, ix = gx0 + pxx;
        u16 v = 0;
        if (iy < 357 && ix < 357)
            v = ga[in_off + ((long)(n * 16 + c) * 357 + iy) * 357 + ix];
        patch[i] = v;
    }
    for (int i = threadIdx.x; i < 4608; i += 256) {
        int o = i % 32, k = i / 32;
        w3s[i] = ga[w3o + o * 144 + k];
    }
    for (int i = threadIdx.x; i < 32; i += 256) { b3f[i] = us2f(ga[b3o + i]); a3f[i] = us2f(ga[a3o + i]); }
    for (int i = threadIdx.x; i < 64; i += 256) w41f[i] = us2f(ga[w41o + i]);
    for (int i = threadIdx.x; i < 128; i += 256) w42f[i] = us2f(ga[w42o + i]);
    if (threadIdx.x < 2) b41f[threadIdx.x] = us2f(ga[b41o + threadIdx.x]);
    if (threadIdx.x < 4) b42f[threadIdx.x] = us2f(ga[b42o + threadIdx.x]);
    __syncthreads();

    int lane = threadIdx.x & 63, og = threadIdx.x >> 6;    // 4 groups, OPT=8
    int pb[4];
    #pragma unroll
    for (int r = 0; r < 4; ++r) {
        int p = lane + 64 * r;
        pb[r] = (p >> 5) * 34 + (p & 31);
    }
    float acc[4][8];
    #pragma unroll
    for (int r = 0; r < 4; ++r)
        #pragma unroll
        for (int j = 0; j < 8; ++j) acc[r][j] = 0.f;

    const uint4* wq = (const uint4*)w3s;
    for (int c = 0; c < 16; ++c) {
        #pragma unroll
        for (int ky = 0; ky < 3; ++ky) {
            #pragma unroll
            for (int kx = 0; kx < 3; ++kx) {
                int k = (c * 3 + ky) * 3 + kx;
                int ub = c * 340 + ky * 34 + kx;
                float a[4];
                #pragma unroll
                for (int r = 0; r < 4; ++r) a[r] = us2f(patch[ub + pb[r]]);
                uint4 q = wq[k * 4 + og];
                float wv[8];
                wv[0]=ulo(q.x); wv[1]=uhi(q.x); wv[2]=ulo(q.y); wv[3]=uhi(q.y);
                wv[4]=ulo(q.z); wv[5]=uhi(q.z); wv[6]=ulo(q.w); wv[7]=uhi(q.w);
                #pragma unroll
                for (int r = 0; r < 4; ++r)
                    #pragma unroll
                    for (int j = 0; j < 8; ++j)
                        acc[r][j] += a[r] * wv[j];
            }
        }
    }
    #pragma unroll
    for (int j = 0; j < 8; ++j) {
        int o = og * 8 + j;
        float b = b3f[o], al = a3f[o];
        #pragma unroll
        for (int r = 0; r < 4; ++r) {
            int p = lane + 64 * r;
            float v = acc[r][j] + b;
            v = v > 0.f ? v : v * al;
            c3s[p * 33 + o] = v;
        }
    }
    __syncthreads();

    int p = threadIdx.x;
    int gy = gy0 + (p >> 5), gx = gx0 + (p & 31);
    if (gy < 355 && gx < 355) {
        int f32 = g_isf32;
        float l0 = b41f[0], l1 = b41f[1];
        float r0 = b42f[0], r1 = b42f[1], r2 = b42f[2], r3 = b42f[3];
        #pragma unroll
        for (int o = 0; o < 32; ++o) {
            float v = c3s[p * 33 + o];
            l0 += v * w41f[o];
            l1 += v * w41f[32 + o];
            r0 += v * w42f[o];
            r1 += v * w42f[32 + o];
            r2 += v * w42f[64 + o];
            r3 += v * w42f[96 + o];
        }
        float mx = fmaxf(l0, l1);
        float e0 = __expf(l0 - mx), e1 = __expf(l1 - mx);
        float inv = 1.f / (e0 + e1);
        const long HW = 355L * 355L;
        long pix = (long)gy * 355 + gx;
        stout(dout, 4032800 + ((long)n * 2 + 0) * HW + pix, e0 * inv, f32);
        stout(dout, 4032800 + ((long)n * 2 + 1) * HW + pix, e1 * inv, f32);
        stout(dout, ((long)n * 4 + 0) * HW + pix, r0, f32);
        stout(dout, ((long)n * 4 + 1) * HW + pix, r1, f32);
        stout(dout, ((long)n * 4 + 2) * HW + pix, r2, f32);
        stout(dout, ((long)n * 4 + 3) * HW + pix, r3, f32);
    }
}

// ---------------------------------------------------------------------------
// MaxPool2d, ceil_mode (OOB taps skipped).
// ---------------------------------------------------------------------------
__global__ void maxpool_kern(int in_off, int out_off,
                             int H, int W, int OH, int OW, int k, int s, int total)
{
    int tid = blockIdx.x * blockDim.x + threadIdx.x;
    if (tid >= total) return;
    int x = tid % OW;
    int t = tid / OW;
    int y = t % OH;
    int nc = t / OH;
    const bf16* ip = g_arena + in_off + (long)nc * H * W;
    int sy = y * s, sx = x * s;
    float m = -1e30f;
    for (int ky = 0; ky < k; ++ky) {
        int iy = sy + ky;
        if (iy >= H) break;
        for (int kx = 0; kx < k; ++kx) {
            int ix = sx + kx;
            if (ix >= W) break;
            m = fmaxf(m, b2f(ip[iy * W + ix]));
        }
    }
    g_arena[(long)out_off + tid] = f2b(m);
}

// ---------------------------------------------------------------------------
// Flatten: torch permute(0,3,2,1).view -> out[n][w*H*C + h*C + c]
// ---------------------------------------------------------------------------
__global__ void flatten_kern(int in_off, int out_off, int C, int H, int W, int total)
{
    int tid = blockIdx.x * blockDim.x + threadIdx.x;
    if (tid >= total) return;
    int CHW = C * H * W;
    int n = tid / CHW;
    int k = tid % CHW;
    int w = k / (H * C);
    int r = k % (H * C);
    int h = r / C;
    int c = r % C;
    g_arena[(long)out_off + tid] = g_arena[in_off + (((long)n * C + c) * H + h) * W + w];
}

// ---------------------------------------------------------------------------
// Dense + bias + PReLU.
// ---------------------------------------------------------------------------
__global__ void dense_prelu_kern(int in_off, int w_off, int b_off, int a_off, int out_off,
                                 int K, int J, int total)
{
    int tid = blockIdx.x * blockDim.x + threadIdx.x;
    if (tid >= total) return;
    int j = tid % J;
    int n = tid / J;
    const bf16* ip = g_arena + in_off + (long)n * K;
    const bf16* wp = g_arena + w_off + (long)j * K;
    float acc = b2f(g_arena[b_off + j]);
    for (int k = 0; k < K; ++k)
        acc += b2f(ip[k]) * b2f(wp[k]);
    float a = b2f(g_arena[a_off + j]);
    acc = acc > 0.f ? acc : acc * a;
    g_arena[(long)out_off + tid] = f2b(acc);
}

// ---------------------------------------------------------------------------
// R/O-Net heads.
// ---------------------------------------------------------------------------
__global__ void heads_kern(int fc_off, int wSo, int bSo, int w1o, int b1o,
                           int w2o, int b2o, void* dout,
                           long outS_off, long out1_off, long out2_off,
                           int N, int K, int J1, int J2)
{
    int n = blockIdx.x * blockDim.x + threadIdx.x;
    if (n >= N) return;
    int f32 = g_isf32;
    const bf16* f = g_arena + fc_off + (long)n * K;
    float l0 = b2f(g_arena[bSo + 0]), l1 = b2f(g_arena[bSo + 1]);
    const bf16* wS = g_arena + wSo;
    for (int k = 0; k < K; ++k) {
        float v = b2f(f[k]);
        l0 += v * b2f(wS[k]);
        l1 += v * b2f(wS[K + k]);
    }
    float m = fmaxf(l0, l1);
    float e0 = __expf(l0 - m), e1 = __expf(l1 - m);
    float inv = 1.f / (e0 + e1);
    stout(dout, outS_off + (long)n * 2 + 0, e0 * inv, f32);
    stout(dout, outS_off + (long)n * 2 + 1, e1 * inv, f32);
    for (int j = 0; j < J1; ++j) {
        float acc = b2f(g_arena[b1o + j]);
        const bf16* wp = g_arena + w1o + (long)j * K;
        for (int k = 0; k < K; ++k)
            acc += b2f(f[k]) * b2f(wp[k]);
        stout(dout, out1_off + (long)n * J1 + j, acc, f32);
    }
    if (J2 > 0) {
        for (int j = 0; j < J2; ++j) {
            float acc = b2f(g_arena[b2o + j]);
            const bf16* wp = g_arena + w2o + (long)j * K;
            for (int k = 0; k < K; ++k)
                acc += b2f(f[k]) * b2f(wp[k]);
            stout(dout, out2_off + (long)n * J2 + j, acc, f32);
        }
    }
}

static inline dim3 g1(int total) { return dim3((unsigned)((total + 255) / 256)); }

extern "C" void kernel_launch(void* const* d_in, const int* in_sizes, int n_in,
                              void* d_out, int out_size, void* d_ws, size_t ws_size,
                              hipStream_t stream)
{
    int woff[53];
    int acc = OFF_WTS;
    int mx = 0;
    for (int i = 3; i < 53; ++i) { woff[i] = acc; acc += in_sizes[i]; if (in_sizes[i] > mx) mx = in_sizes[i]; }

    detect_kern<<<1, 64, 0, stream>>>(d_in[0]);
    convert_kern<<<g1(12441600), 256, 0, stream>>>(d_in[0], OFF_IMGS, 12441600);
    convert_kern<<<g1(3538944), 256, 0, stream>>>(d_in[1], OFF_C24, 3538944);
    convert_kern<<<g1(3538944), 256, 0, stream>>>(d_in[2], OFF_C48, 3538944);
    CvtTab tab;
    for (int i = 3; i < 53; ++i) tab.e[i - 3] = CvtEnt{ d_in[i], woff[i], in_sizes[i] };
    convert_many_kern<<<dim3((unsigned)((mx + 255) / 256), 50), 256, 0, stream>>>(tab);

    // ================= PNet =================
    pnet_c1p_kern<<<dim3(8, 23, 23), 256, 0, stream>>>(woff[3], woff[4], woff[5], OFF_A);
    pnet_c2_kern<<<dim3(8, 12, 12), 256, 0, stream>>>(OFF_A, woff[6], woff[7], woff[8], OFF_B);
    pnet_c3h_kern<<<dim3(8, 45, 12), 256, 0, stream>>>(OFF_B,
        woff[9], woff[10], woff[11], woff[12], woff[13], woff[14], woff[15], d_out);

    // ================= RNet =================
    conv_a_kern<3,3,3,24,24,22,22,28,32,4><<<dim3(2048, 4, 1), 256, 0, stream>>>(
        OFF_C24, woff[16], woff[17], woff[18], OFF_A);
    maxpool_kern<<<g1(6938624), 256, 0, stream>>>(OFF_A, OFF_B, 22, 22, 11, 11, 3, 2, 6938624);
    conv_a_kern<28,3,3,11,11,9,9,48,48,3><<<dim3(2048, 1, 1), 256, 0, stream>>>(
        OFF_B, woff[19], woff[20], woff[21], OFF_A);
    maxpool_kern<<<g1(1572864), 256, 0, stream>>>(OFF_A, OFF_B, 9, 9, 4, 4, 3, 2, 1572864);
    conv_a_kern<48,2,2,4,4,3,3,64,64,1><<<dim3(2048, 1, 1), 256, 0, stream>>>(
        OFF_B, woff[22], woff[23], woff[24], OFF_A);
    flatten_kern<<<g1(1179648), 256, 0, stream>>>(OFF_A, OFF_B, 64, 3, 3, 1179648);
    dense_prelu_kern<<<g1(262144), 256, 0, stream>>>(OFF_B, woff[25], woff[26], woff[27], OFF_A,
        576, 128, 262144);
    heads_kern<<<g1(2048), 256, 0, stream>>>(OFF_A, woff[28], woff[29], woff[30], woff[31],
        0, 0, d_out, 6057392L, 6049200L, 0L, 2048, 128, 4, 0);

    // ================= ONet =================
    conv_a_kern<3,3,3,48,48,46,46,32,32,4><<<dim3(512, 17, 1), 256, 0, stream>>>(
        OFF_C48, woff[32], woff[33], woff[34], OFF_A);
    maxpool_kern<<<g1(8667136), 256, 0, stream>>>(OFF_A, OFF_B, 46, 46, 23, 23, 3, 2, 8667136);
    conv_a_kern<32,3,3,23,23,21,21,64,64,4><<<dim3(512, 4, 1), 256, 0, stream>>>(
        OFF_B, woff[35], woff[36], woff[37], OFF_A);
    maxpool_kern<<<g1(3276800), 256, 0, stream>>>(OFF_A, OFF_B, 21, 21, 10, 10, 3, 2, 3276800);
    conv_a_kern<64,3,3,10,10,8,8,64,32,2><<<dim3(512, 1, 2), 256, 0, stream>>>(
        OFF_B, woff[38], woff[39], woff[40], OFF_A);
    maxpool_kern<<<g1(524288), 256, 0, stream>>>(OFF_A, OFF_B, 8, 8, 4, 4, 2, 2, 524288);
    conv_a_kern<64,2,2,4,4,3,3,128,64,1><<<dim3(512, 1, 2), 256, 0, stream>>>(
        OFF_B, woff[41], woff[42], woff[43], OFF_A);
    flatten_kern<<<g1(589824), 256, 0, stream>>>(OFF_A, OFF_B, 128, 3, 3, 589824);
    dense_prelu_kern<<<g1(131072), 256, 0, stream>>>(OFF_B, woff[44], woff[45], woff[46], OFF_A,
        1152, 256, 131072);
    heads_kern<<<g1(512), 256, 0, stream>>>(OFF_A, woff[47], woff[48], woff[49], woff[50],
        woff[51], woff[52], d_out, 6068656L, 6061488L, 6063536L, 512, 256, 4, 10);
}

// Round 5
// 2275.698 us; speedup vs baseline: 2.9924x; 1.2523x over previous
//
#include <hip/hip_runtime.h>
#include <hip/hip_bf16.h>

typedef __hip_bfloat16 bf16;
typedef unsigned short u16;
typedef unsigned int u32;

__device__ __forceinline__ float b2f(bf16 v) { return __bfloat162float(v); }
__device__ __forceinline__ bf16  f2b(float v) { return __float2bfloat16(v); }
__device__ __forceinline__ float us2f(u16 u) { return __uint_as_float((u32)u << 16); }
__device__ __forceinline__ float ulo(u32 u)  { return __uint_as_float(u << 16); }
__device__ __forceinline__ float uhi(u32 u)  { return __uint_as_float(u & 0xFFFF0000u); }

// ---------------------------------------------------------------------------
// Static device arena (BSS, ~143 MB): converted inputs + weights + scratch.
// ---------------------------------------------------------------------------
#define OFF_IMGS 0
#define OFF_C24  12441600
#define OFF_C48  15980544
#define OFF_WTS  19519488
#define OFF_A    20119488
#define OFF_B    54819488
#define ARENA_N  71319488L

__device__ bf16 g_arena[ARENA_N];
__device__ int  g_isf32;

// ---------------------------------------------------------------------------
// Dtype detection (bf16 N(0,1) never has exponent >= 0x8D; fp32 misread does).
// ---------------------------------------------------------------------------
__global__ void detect_kern(const void* imgs)
{
    if (threadIdx.x != 0) return;
    const u16* u = (const u16*)imgs;
    int f32 = 0;
    for (int i = 0; i < 256; ++i) {
        int e = (u[i] >> 7) & 0xFF;
        if (e >= 0x8D) f32 = 1;
    }
    g_isf32 = f32;
}

__global__ void convert_kern(const void* __restrict__ src, int dst_off, int n)
{
    int i = blockIdx.x * blockDim.x + threadIdx.x;
    if (i >= n) return;
    float v = g_isf32 ? ((const float*)src)[i] : b2f(((const bf16*)src)[i]);
    g_arena[(long)dst_off + i] = f2b(v);
}

struct CvtEnt { const void* src; int dst_off; int n; };
struct CvtTab { CvtEnt e[50]; };
__global__ void convert_many_kern(CvtTab tab)
{
    CvtEnt ent = tab.e[blockIdx.y];
    int i = blockIdx.x * blockDim.x + threadIdx.x;
    if (i >= ent.n) return;
    float v = g_isf32 ? ((const float*)ent.src)[i] : b2f(((const bf16*)ent.src)[i]);
    g_arena[(long)ent.dst_off + i] = f2b(v);
}

__device__ __forceinline__ void stout(void* base, long idx, float v, int f32)
{
    if (f32) ((float*)base)[idx] = v;
    else     ((bf16*)base)[idx] = f2b(v);
}

// ---------------------------------------------------------------------------
// Generic LDS-resident conv for crop nets (whole image fits in LDS).
// ---------------------------------------------------------------------------
template<int CIN,int KH,int KW,int H,int W,int OH,int OW,int CO,int OBLK,int R>
__launch_bounds__(256)
__global__ void conv_a_kern(int in_off, int w_off, int b_off, int a_off, int out_off)
{
    constexpr int KTOT = CIN * KH * KW;
    constexpr int INCNT = CIN * H * W;
    constexpr int OPT = OBLK / 8;
    constexpr int NPX = OH * OW;
    __shared__ __align__(16) u16 in_s[INCNT];
    __shared__ __align__(16) u16 w_s[KTOT * OBLK];

    int n = blockIdx.x, pxc = blockIdx.y, oc = blockIdx.z;
    const u16* ga = (const u16*)g_arena;

    const u32* src = (const u32*)(ga + in_off + (long)n * INCNT);
    u32* dst = (u32*)in_s;
    for (int i = threadIdx.x; i < INCNT / 2; i += 256) dst[i] = src[i];
    for (int i = threadIdx.x; i < KTOT * OBLK; i += 256) {
        int o_l = i % OBLK, k = i / OBLK;
        int o = oc * OBLK + o_l;
        w_s[i] = (o < CO) ? ga[w_off + (long)o * KTOT + k] : (u16)0;
    }
    __syncthreads();

    int lane = threadIdx.x & 31, og = threadIdx.x >> 5;
    int pixoff[R], pxg[R];
    bool vld[R];
    #pragma unroll
    for (int r = 0; r < R; ++r) {
        int px = pxc * (32 * R) + lane + r * 32;
        vld[r] = px < NPX;
        int p = vld[r] ? px : 0;
        pxg[r] = p;
        pixoff[r] = (p / OW) * W + (p % OW);
    }
    float acc[R][OPT];
    #pragma unroll
    for (int r = 0; r < R; ++r)
        #pragma unroll
        for (int j = 0; j < OPT; ++j) acc[r][j] = 0.f;

    const u32* wu = (const u32*)w_s;
    for (int c = 0; c < CIN; ++c) {
        #pragma unroll
        for (int ky = 0; ky < KH; ++ky) {
            #pragma unroll
            for (int kx = 0; kx < KW; ++kx) {
                int k = (c * KH + ky) * KW + kx;
                int ub = c * (H * W) + ky * W + kx;
                float a[R];
                #pragma unroll
                for (int r = 0; r < R; ++r) a[r] = us2f(in_s[ub + pixoff[r]]);
                int wb = (k * OBLK + og * OPT) >> 1;
                float wv[OPT];
                #pragma unroll
                for (int jj = 0; jj < OPT / 2; ++jj) {
                    u32 u = wu[wb + jj];
                    wv[2 * jj] = ulo(u); wv[2 * jj + 1] = uhi(u);
                }
                #pragma unroll
                for (int r = 0; r < R; ++r)
                    #pragma unroll
                    for (int j = 0; j < OPT; ++j)
                        acc[r][j] += a[r] * wv[j];
            }
        }
    }
    #pragma unroll
    for (int j = 0; j < OPT; ++j) {
        int o = oc * OBLK + og * OPT + j;
        if (o < CO) {
            float b = us2f(ga[b_off + o]);
            float al = us2f(ga[a_off + o]);
            #pragma unroll
            for (int r = 0; r < R; ++r) if (vld[r]) {
                float v = acc[r][j] + b;
                v = v > 0.f ? v : v * al;
                g_arena[(long)out_off + ((long)n * CO + o) * NPX + pxg[r]] = f2b(v);
            }
        }
    }
}

// ---------------------------------------------------------------------------
// PNet conv1 (3->10) + PReLU + maxpool 2x2 s2.
// ---------------------------------------------------------------------------
__launch_bounds__(256)
__global__ void pnet_c1p_kern(int w_off, int b_off, int a_off, int out_off)
{
    __shared__ u16 patch[3 * 34 * 34];
    __shared__ __align__(16) u16 w_s[27 * 16];
    int n = blockIdx.x, pty = blockIdx.y, ptx = blockIdx.z;
    int cy0 = pty * 32, cx0 = ptx * 32;
    const u16* ga = (const u16*)g_arena;

    for (int i = threadIdx.x; i < 3468; i += 256) {
        int c = i / 1156, rem = i % 1156, py = rem / 34, pxx = rem % 34;
        int iy = cy0 + py, ix = cx0 + pxx;
        u16 v = 0;
        if (iy < 720 && ix < 720)
            v = ga[OFF_IMGS + ((long)(n * 3 + c) * 720 + iy) * 720 + ix];
        patch[i] = v;
    }
    for (int i = threadIdx.x; i < 27 * 16; i += 256) {
        int o = i % 16, k = i / 16;
        w_s[i] = (o < 10) ? ga[w_off + o * 27 + k] : (u16)0;
    }
    __syncthreads();

    int px = threadIdx.x % 16, py = threadIdx.x / 16;
    float acc[2][2][10];
    #pragma unroll
    for (int a = 0; a < 2; ++a)
        #pragma unroll
        for (int b = 0; b < 2; ++b)
            #pragma unroll
            for (int o = 0; o < 10; ++o) acc[a][b][o] = 0.f;

    const uint4* wq = (const uint4*)w_s;
    for (int c = 0; c < 3; ++c) {
        #pragma unroll
        for (int ky = 0; ky < 3; ++ky) {
            #pragma unroll
            for (int kx = 0; kx < 3; ++kx) {
                int k = (c * 3 + ky) * 3 + kx;
                float a[2][2];
                #pragma unroll
                for (int dy = 0; dy < 2; ++dy)
                    #pragma unroll
                    for (int dx = 0; dx < 2; ++dx)
                        a[dy][dx] = us2f(patch[c * 1156 + (2 * py + dy + ky) * 34 + (2 * px + dx + kx)]);
                uint4 q0 = wq[k * 2], q1 = wq[k * 2 + 1];
                float wv[10];
                wv[0] = ulo(q0.x); wv[1] = uhi(q0.x); wv[2] = ulo(q0.y); wv[3] = uhi(q0.y);
                wv[4] = ulo(q0.z); wv[5] = uhi(q0.z); wv[6] = ulo(q0.w); wv[7] = uhi(q0.w);
                wv[8] = ulo(q1.x); wv[9] = uhi(q1.x);
                #pragma unroll
                for (int o = 0; o < 10; ++o)
                    #pragma unroll
                    for (int dy = 0; dy < 2; ++dy)
                        #pragma unroll
                        for (int dx = 0; dx < 2; ++dx)
                            acc[dy][dx][o] += a[dy][dx] * wv[o];
            }
        }
    }
    int pgy = pty * 16 + py, pgx = ptx * 16 + px;
    if (pgy < 359 && pgx < 359) {
        #pragma unroll
        for (int o = 0; o < 10; ++o) {
            float b = us2f(ga[b_off + o]);
            float al = us2f(ga[a_off + o]);
            float m = -1e30f;
            #pragma unroll
            for (int dy = 0; dy < 2; ++dy)
                #pragma unroll
                for (int dx = 0; dx < 2; ++dx) {
                    float v = acc[dy][dx][o] + b;
                    v = v > 0.f ? v : v * al;
                    m = fmaxf(m, v);
                }
            g_arena[(long)out_off + ((long)(n * 10 + o) * 359 + pgy) * 359 + pgx] = f2b(m);
        }
    }
}

// ---------------------------------------------------------------------------
// PNet conv2 (10->16).
// ---------------------------------------------------------------------------
__launch_bounds__(256)
__global__ void pnet_c2_kern(int in_off, int w_off, int b_off, int a_off, int out_off)
{
    __shared__ u16 patch[10 * 34 * 34];
    __shared__ __align__(16) u16 w_s[90 * 16];
    int n = blockIdx.x, ty = blockIdx.y, tx = blockIdx.z;
    int y0 = ty * 32, x0 = tx * 32;
    const u16* ga = (const u16*)g_arena;

    for (int i = threadIdx.x; i < 11560; i += 256) {
        int c = i / 1156, rem = i % 1156, py = rem / 34, pxx = rem % 34;
        int iy = y0 + py, ix = x0 + pxx;
        u16 v = 0;
        if (iy < 359 && ix < 359)
            v = ga[in_off + ((long)(n * 10 + c) * 359 + iy) * 359 + ix];
        patch[i] = v;
    }
    for (int i = threadIdx.x; i < 1440; i += 256) {
        int o = i % 16, k = i / 16;
        w_s[i] = ga[w_off + o * 90 + k];
    }
    __syncthreads();

    int x = threadIdx.x % 32, yg = threadIdx.x / 32;
    float acc[4][16];
    #pragma unroll
    for (int r = 0; r < 4; ++r)
        #pragma unroll
        for (int o = 0; o < 16; ++o) acc[r][o] = 0.f;

    const uint4* wq = (const uint4*)w_s;
    for (int c = 0; c < 10; ++c) {
        #pragma unroll
        for (int ky = 0; ky < 3; ++ky) {
            #pragma unroll
            for (int kx = 0; kx < 3; ++kx) {
                int k = (c * 3 + ky) * 3 + kx;
                float a[4];
                #pragma unroll
                for (int r = 0; r < 4; ++r)
                    a[r] = us2f(patch[c * 1156 + (yg + 8 * r + ky) * 34 + (x + kx)]);
                uint4 q0 = wq[k * 2], q1 = wq[k * 2 + 1];
                float wv[16];
                wv[0]=ulo(q0.x); wv[1]=uhi(q0.x); wv[2]=ulo(q0.y); wv[3]=uhi(q0.y);
                wv[4]=ulo(q0.z); wv[5]=uhi(q0.z); wv[6]=ulo(q0.w); wv[7]=uhi(q0.w);
                wv[8]=ulo(q1.x); wv[9]=uhi(q1.x); wv[10]=ulo(q1.y); wv[11]=uhi(q1.y);
                wv[12]=ulo(q1.z); wv[13]=uhi(q1.z); wv[14]=ulo(q1.w); wv[15]=uhi(q1.w);
                #pragma unroll
                for (int r = 0; r < 4; ++r)
                    #pragma unroll
                    for (int o = 0; o < 16; ++o)
                        acc[r][o] += a[r] * wv[o];
            }
        }
    }
    #pragma unroll
    for (int o = 0; o < 16; ++o) {
        float b = us2f(ga[b_off + o]);
        float al = us2f(ga[a_off + o]);
        #pragma unroll
        for (int r = 0; r < 4; ++r) {
            int gy = y0 + yg + 8 * r, gx = x0 + x;
            if (gy < 357 && gx < 357) {
                float v = acc[r][o] + b;
                v = v > 0.f ? v : v * al;
                g_arena[(long)out_off + ((long)(n * 16 + o) * 357 + gy) * 357 + gx] = f2b(v);
            }
        }
    }
}

// ---------------------------------------------------------------------------
// PNet conv3 (16->32) + PReLU + 1x1 heads + softmax, fused.
// ---------------------------------------------------------------------------
__launch_bounds__(256)
__global__ void pnet_c3h_kern(int in_off, int w3o, int b3o, int a3o,
                              int w41o, int b41o, int w42o, int b42o, void* dout)
{
    __shared__ u16 patch[16 * 10 * 34];
    __shared__ __align__(16) u16 w3s[144 * 32];
    __shared__ float c3s[256 * 33];
    __shared__ float b3f[32], a3f[32], w41f[64], w42f[128], b41f[2], b42f[4];

    int n = blockIdx.x, by = blockIdx.y, tx = blockIdx.z;
    int gy0 = by * 8, gx0 = tx * 32;
    const u16* ga = (const u16*)g_arena;

    for (int i = threadIdx.x; i < 5440; i += 256) {
        int c = i / 340, rem = i % 340, py = rem / 34, pxx = rem % 34;
        int iy = gy0 + py, ix = gx0 + pxx;
        u16 v = 0;
        if (iy < 357 && ix < 357)
            v = ga[in_off + ((long)(n * 16 + c) * 357 + iy) * 357 + ix];
        patch[i] = v;
    }
    for (int i = threadIdx.x; i < 4608; i += 256) {
        int o = i % 32, k = i / 32;
        w3s[i] = ga[w3o + o * 144 + k];
    }
    for (int i = threadIdx.x; i < 32; i += 256) { b3f[i] = us2f(ga[b3o + i]); a3f[i] = us2f(ga[a3o + i]); }
    for (int i = threadIdx.x; i < 64; i += 256) w41f[i] = us2f(ga[w41o + i]);
    for (int i = threadIdx.x; i < 128; i += 256) w42f[i] = us2f(ga[w42o + i]);
    if (threadIdx.x < 2) b41f[threadIdx.x] = us2f(ga[b41o + threadIdx.x]);
    if (threadIdx.x < 4) b42f[threadIdx.x] = us2f(ga[b42o + threadIdx.x]);
    __syncthreads();

    int lane = threadIdx.x & 63, og = threadIdx.x >> 6;
    int pb[4];
    #pragma unroll
    for (int r = 0; r < 4; ++r) {
        int p = lane + 64 * r;
        pb[r] = (p >> 5) * 34 + (p & 31);
    }
    float acc[4][8];
    #pragma unroll
    for (int r = 0; r < 4; ++r)
        #pragma unroll
        for (int j = 0; j < 8; ++j) acc[r][j] = 0.f;

    const uint4* wq = (const uint4*)w3s;
    for (int c = 0; c < 16; ++c) {
        #pragma unroll
        for (int ky = 0; ky < 3; ++ky) {
            #pragma unroll
            for (int kx = 0; kx < 3; ++kx) {
                int k = (c * 3 + ky) * 3 + kx;
                int ub = c * 340 + ky * 34 + kx;
                float a[4];
                #pragma unroll
                for (int r = 0; r < 4; ++r) a[r] = us2f(patch[ub + pb[r]]);
                uint4 q = wq[k * 4 + og];
                float wv[8];
                wv[0]=ulo(q.x); wv[1]=uhi(q.x); wv[2]=ulo(q.y); wv[3]=uhi(q.y);
                wv[4]=ulo(q.z); wv[5]=uhi(q.z); wv[6]=ulo(q.w); wv[7]=uhi(q.w);
                #pragma unroll
                for (int r = 0; r < 4; ++r)
                    #pragma unroll
                    for (int j = 0; j < 8; ++j)
                        acc[r][j] += a[r] * wv[j];
            }
        }
    }
    #pragma unroll
    for (int j = 0; j < 8; ++j) {
        int o = og * 8 + j;
        float b = b3f[o], al = a3f[o];
        #pragma unroll
        for (int r = 0; r < 4; ++r) {
            int p = lane + 64 * r;
            float v = acc[r][j] + b;
            v = v > 0.f ? v : v * al;
            c3s[p * 33 + o] = v;
        }
    }
    __syncthreads();

    int p = threadIdx.x;
    int gy = gy0 + (p >> 5), gx = gx0 + (p & 31);
    if (gy < 355 && gx < 355) {
        int f32 = g_isf32;
        float l0 = b41f[0], l1 = b41f[1];
        float r0 = b42f[0], r1 = b42f[1], r2 = b42f[2], r3 = b42f[3];
        #pragma unroll
        for (int o = 0; o < 32; ++o) {
            float v = c3s[p * 33 + o];
            l0 += v * w41f[o];
            l1 += v * w41f[32 + o];
            r0 += v * w42f[o];
            r1 += v * w42f[32 + o];
            r2 += v * w42f[64 + o];
            r3 += v * w42f[96 + o];
        }
        float mx = fmaxf(l0, l1);
        float e0 = __expf(l0 - mx), e1 = __expf(l1 - mx);
        float inv = 1.f / (e0 + e1);
        const long HW = 355L * 355L;
        long pix = (long)gy * 355 + gx;
        stout(dout, 4032800 + ((long)n * 2 + 0) * HW + pix, e0 * inv, f32);
        stout(dout, 4032800 + ((long)n * 2 + 1) * HW + pix, e1 * inv, f32);
        stout(dout, ((long)n * 4 + 0) * HW + pix, r0, f32);
        stout(dout, ((long)n * 4 + 1) * HW + pix, r1, f32);
        stout(dout, ((long)n * 4 + 2) * HW + pix, r2, f32);
        stout(dout, ((long)n * 4 + 3) * HW + pix, r3, f32);
    }
}

// ---------------------------------------------------------------------------
// MaxPool2d, ceil_mode (OOB taps skipped).
// ---------------------------------------------------------------------------
__global__ void maxpool_kern(int in_off, int out_off,
                             int H, int W, int OH, int OW, int k, int s, int total)
{
    int tid = blockIdx.x * blockDim.x + threadIdx.x;
    if (tid >= total) return;
    int x = tid % OW;
    int t = tid / OW;
    int y = t % OH;
    int nc = t / OH;
    const bf16* ip = g_arena + in_off + (long)nc * H * W;
    int sy = y * s, sx = x * s;
    float m = -1e30f;
    for (int ky = 0; ky < k; ++ky) {
        int iy = sy + ky;
        if (iy >= H) break;
        for (int kx = 0; kx < k; ++kx) {
            int ix = sx + kx;
            if (ix >= W) break;
            m = fmaxf(m, b2f(ip[iy * W + ix]));
        }
    }
    g_arena[(long)out_off + tid] = f2b(m);
}

// ---------------------------------------------------------------------------
// Flatten: torch permute(0,3,2,1).view -> out[n][w*H*C + h*C + c]
// ---------------------------------------------------------------------------
__global__ void flatten_kern(int in_off, int out_off, int C, int H, int W, int total)
{
    int tid = blockIdx.x * blockDim.x + threadIdx.x;
    if (tid >= total) return;
    int CHW = C * H * W;
    int n = tid / CHW;
    int k = tid % CHW;
    int w = k / (H * C);
    int r = k % (H * C);
    int h = r / C;
    int c = r % C;
    g_arena[(long)out_off + tid] = g_arena[in_off + (((long)n * C + c) * H + h) * W + w];
}

// ---------------------------------------------------------------------------
// Dense + bias + PReLU.
// ---------------------------------------------------------------------------
__global__ void dense_prelu_kern(int in_off, int w_off, int b_off, int a_off, int out_off,
                                 int K, int J, int total)
{
    int tid = blockIdx.x * blockDim.x + threadIdx.x;
    if (tid >= total) return;
    int j = tid % J;
    int n = tid / J;
    const bf16* ip = g_arena + in_off + (long)n * K;
    const bf16* wp = g_arena + w_off + (long)j * K;
    float acc = b2f(g_arena[b_off + j]);
    for (int k = 0; k < K; ++k)
        acc += b2f(ip[k]) * b2f(wp[k]);
    float a = b2f(g_arena[a_off + j]);
    acc = acc > 0.f ? acc : acc * a;
    g_arena[(long)out_off + tid] = f2b(acc);
}

// ---------------------------------------------------------------------------
// Heads, wave-per-sample: 64 lanes partition K; coalesced loads of fc row and
// every weight row; butterfly shuffle reduction; lane 0 softmax + stores.
// NACC = 2 + J1 + J2 partial sums per lane.
// ---------------------------------------------------------------------------
template<int K, int J1, int J2>
__launch_bounds__(256)
__global__ void heads_wave_kern(int fc_off, int wSo, int bSo, int w1o, int b1o,
                                int w2o, int b2o, void* dout,
                                long outS_off, long out1_off, long out2_off, int N)
{
    constexpr int KPL = K / 64;
    constexpr int NACC = 2 + J1 + J2;
    int wave = (blockIdx.x * blockDim.x + threadIdx.x) >> 6;
    int lane = threadIdx.x & 63;
    if (wave >= N) return;
    const u16* ga = (const u16*)g_arena;
    const u16* f  = ga + fc_off + (long)wave * K;
    const u16* wS = ga + wSo;
    const u16* w1 = ga + w1o;
    const u16* w2 = ga + w2o;

    float acc[NACC];
    #pragma unroll
    for (int j = 0; j < NACC; ++j) acc[j] = 0.f;

    #pragma unroll
    for (int kk = 0; kk < KPL; ++kk) {
        int k = lane + kk * 64;
        float fv = us2f(f[k]);
        acc[0] += fv * us2f(wS[k]);
        acc[1] += fv * us2f(wS[K + k]);
        #pragma unroll
        for (int j = 0; j < J1; ++j)
            acc[2 + j] += fv * us2f(w1[j * K + k]);
        #pragma unroll
        for (int j = 0; j < J2; ++j)
            acc[2 + J1 + j] += fv * us2f(w2[j * K + k]);
    }
    #pragma unroll
    for (int j = 0; j < NACC; ++j)
        #pragma unroll
        for (int off = 32; off > 0; off >>= 1)
            acc[j] += __shfl_xor(acc[j], off, 64);

    if (lane == 0) {
        int f32 = g_isf32;
        float l0 = acc[0] + us2f(ga[bSo + 0]);
        float l1 = acc[1] + us2f(ga[bSo + 1]);
        float m = fmaxf(l0, l1);
        float e0 = __expf(l0 - m), e1 = __expf(l1 - m);
        float inv = 1.f / (e0 + e1);
        stout(dout, outS_off + (long)wave * 2 + 0, e0 * inv, f32);
        stout(dout, outS_off + (long)wave * 2 + 1, e1 * inv, f32);
        #pragma unroll
        for (int j = 0; j < J1; ++j)
            stout(dout, out1_off + (long)wave * J1 + j, acc[2 + j] + us2f(ga[b1o + j]), f32);
        #pragma unroll
        for (int j = 0; j < J2; ++j)
            stout(dout, out2_off + (long)wave * J2 + j, acc[2 + J1 + j] + us2f(ga[b2o + j]), f32);
    }
}

static inline dim3 g1(int total) { return dim3((unsigned)((total + 255) / 256)); }

extern "C" void kernel_launch(void* const* d_in, const int* in_sizes, int n_in,
                              void* d_out, int out_size, void* d_ws, size_t ws_size,
                              hipStream_t stream)
{
    int woff[53];
    int acc = OFF_WTS;
    int mx = 0;
    for (int i = 3; i < 53; ++i) { woff[i] = acc; acc += in_sizes[i]; if (in_sizes[i] > mx) mx = in_sizes[i]; }

    detect_kern<<<1, 64, 0, stream>>>(d_in[0]);
    convert_kern<<<g1(12441600), 256, 0, stream>>>(d_in[0], OFF_IMGS, 12441600);
    convert_kern<<<g1(3538944), 256, 0, stream>>>(d_in[1], OFF_C24, 3538944);
    convert_kern<<<g1(3538944), 256, 0, stream>>>(d_in[2], OFF_C48, 3538944);
    CvtTab tab;
    for (int i = 3; i < 53; ++i) tab.e[i - 3] = CvtEnt{ d_in[i], woff[i], in_sizes[i] };
    convert_many_kern<<<dim3((unsigned)((mx + 255) / 256), 50), 256, 0, stream>>>(tab);

    // ================= PNet =================
    pnet_c1p_kern<<<dim3(8, 23, 23), 256, 0, stream>>>(woff[3], woff[4], woff[5], OFF_A);
    pnet_c2_kern<<<dim3(8, 12, 12), 256, 0, stream>>>(OFF_A, woff[6], woff[7], woff[8], OFF_B);
    pnet_c3h_kern<<<dim3(8, 45, 12), 256, 0, stream>>>(OFF_B,
        woff[9], woff[10], woff[11], woff[12], woff[13], woff[14], woff[15], d_out);

    // ================= RNet =================
    conv_a_kern<3,3,3,24,24,22,22,28,32,4><<<dim3(2048, 4, 1), 256, 0, stream>>>(
        OFF_C24, woff[16], woff[17], woff[18], OFF_A);
    maxpool_kern<<<g1(6938624), 256, 0, stream>>>(OFF_A, OFF_B, 22, 22, 11, 11, 3, 2, 6938624);
    conv_a_kern<28,3,3,11,11,9,9,48,48,3><<<dim3(2048, 1, 1), 256, 0, stream>>>(
        OFF_B, woff[19], woff[20], woff[21], OFF_A);
    maxpool_kern<<<g1(1572864), 256, 0, stream>>>(OFF_A, OFF_B, 9, 9, 4, 4, 3, 2, 1572864);
    conv_a_kern<48,2,2,4,4,3,3,64,64,1><<<dim3(2048, 1, 1), 256, 0, stream>>>(
        OFF_B, woff[22], woff[23], woff[24], OFF_A);
    flatten_kern<<<g1(1179648), 256, 0, stream>>>(OFF_A, OFF_B, 64, 3, 3, 1179648);
    dense_prelu_kern<<<g1(262144), 256, 0, stream>>>(OFF_B, woff[25], woff[26], woff[27], OFF_A,
        576, 128, 262144);
    heads_wave_kern<128,4,0><<<dim3(512), 256, 0, stream>>>(OFF_A,
        woff[28], woff[29], woff[30], woff[31], 0, 0,
        d_out, 6057392L, 6049200L, 0L, 2048);

    // ================= ONet =================
    conv_a_kern<3,3,3,48,48,46,46,32,32,4><<<dim3(512, 17, 1), 256, 0, stream>>>(
        OFF_C48, woff[32], woff[33], woff[34], OFF_A);
    maxpool_kern<<<g1(8667136), 256, 0, stream>>>(OFF_A, OFF_B, 46, 46, 23, 23, 3, 2, 8667136);
    conv_a_kern<32,3,3,23,23,21,21,64,64,4><<<dim3(512, 4, 1), 256, 0, stream>>>(
        OFF_B, woff[35], woff[36], woff[37], OFF_A);
    maxpool_kern<<<g1(3276800), 256, 0, stream>>>(OFF_A, OFF_B, 21, 21, 10, 10, 3, 2, 3276800);
    conv_a_kern<64,3,3,10,10,8,8,64,32,2><<<dim3(512, 1, 2), 256, 0, stream>>>(
        OFF_B, woff[38], woff[39], woff[40], OFF_A);
    maxpool_kern<<<g1(524288), 256, 0, stream>>>(OFF_A, OFF_B, 8, 8, 4, 4, 2, 2, 524288);
    conv_a_kern<64,2,2,4,4,3,3,128,64,1><<<dim3(512, 1, 2), 256, 0, stream>>>(
        OFF_B, woff[41], woff[42], woff[43], OFF_A);
    flatten_kern<<<g1(589824), 256, 0, stream>>>(OFF_A, OFF_B, 128, 3, 3, 589824);
    dense_prelu_kern<<<g1(131072), 256, 0, stream>>>(OFF_B, woff[44], woff[45], woff[46], OFF_A,
        1152, 256, 131072);
    heads_wave_kern<256,4,10><<<dim3(128), 256, 0, stream>>>(OFF_A,
        woff[47], woff[48], woff[49], woff[50], woff[51], woff[52],
        d_out, 6068656L, 6061488L, 6063536L, 512);
}

// Round 6
// 1766.890 us; speedup vs baseline: 3.8542x; 1.2880x over previous
//
#include <hip/hip_runtime.h>
#include <hip/hip_bf16.h>

typedef __hip_bfloat16 bf16;
typedef unsigned short u16;
typedef unsigned int u32;

__device__ __forceinline__ float b2f(bf16 v) { return __bfloat162float(v); }
__device__ __forceinline__ bf16  f2b(float v) { return __float2bfloat16(v); }
__device__ __forceinline__ float us2f(u16 u) { return __uint_as_float((u32)u << 16); }
__device__ __forceinline__ float ulo(u32 u)  { return __uint_as_float(u << 16); }
__device__ __forceinline__ float uhi(u32 u)  { return __uint_as_float(u & 0xFFFF0000u); }

// ---------------------------------------------------------------------------
// Static device arena (BSS, ~143 MB): converted inputs + weights + scratch.
// ---------------------------------------------------------------------------
#define OFF_IMGS 0
#define OFF_C24  12441600
#define OFF_C48  15980544
#define OFF_WTS  19519488
#define OFF_A    20119488
#define OFF_B    54819488
#define ARENA_N  71319488L

__device__ bf16 g_arena[ARENA_N];
__device__ int  g_isf32;

// ---------------------------------------------------------------------------
// Dtype detection (bf16 N(0,1) never has exponent >= 0x8D; fp32 misread does).
// ---------------------------------------------------------------------------
__global__ void detect_kern(const void* imgs)
{
    if (threadIdx.x != 0) return;
    const u16* u = (const u16*)imgs;
    int f32 = 0;
    for (int i = 0; i < 256; ++i) {
        int e = (u[i] >> 7) & 0xFF;
        if (e >= 0x8D) f32 = 1;
    }
    g_isf32 = f32;
}

__global__ void convert_kern(const void* __restrict__ src, int dst_off, int n)
{
    int i = blockIdx.x * blockDim.x + threadIdx.x;
    if (i >= n) return;
    float v = g_isf32 ? ((const float*)src)[i] : b2f(((const bf16*)src)[i]);
    g_arena[(long)dst_off + i] = f2b(v);
}

struct CvtEnt { const void* src; int dst_off; int n; };
struct CvtTab { CvtEnt e[50]; };
__global__ void convert_many_kern(CvtTab tab)
{
    CvtEnt ent = tab.e[blockIdx.y];
    int i = blockIdx.x * blockDim.x + threadIdx.x;
    if (i >= ent.n) return;
    float v = g_isf32 ? ((const float*)ent.src)[i] : b2f(((const bf16*)ent.src)[i]);
    g_arena[(long)ent.dst_off + i] = f2b(v);
}

__device__ __forceinline__ void stout(void* base, long idx, float v, int f32)
{
    if (f32) ((float*)base)[idx] = v;
    else     ((bf16*)base)[idx] = f2b(v);
}

// ---------------------------------------------------------------------------
// Generic LDS-resident conv for crop nets (whole image fits in LDS).
// ---------------------------------------------------------------------------
template<int CIN,int KH,int KW,int H,int W,int OH,int OW,int CO,int OBLK,int R>
__launch_bounds__(256)
__global__ void conv_a_kern(int in_off, int w_off, int b_off, int a_off, int out_off)
{
    constexpr int KTOT = CIN * KH * KW;
    constexpr int INCNT = CIN * H * W;
    constexpr int OPT = OBLK / 8;
    constexpr int NPX = OH * OW;
    __shared__ __align__(16) u16 in_s[INCNT];
    __shared__ __align__(16) u16 w_s[KTOT * OBLK];

    int n = blockIdx.x, pxc = blockIdx.y, oc = blockIdx.z;
    const u16* ga = (const u16*)g_arena;

    const u32* src = (const u32*)(ga + in_off + (long)n * INCNT);
    u32* dst = (u32*)in_s;
    for (int i = threadIdx.x; i < INCNT / 2; i += 256) dst[i] = src[i];
    for (int i = threadIdx.x; i < KTOT * OBLK; i += 256) {
        int o_l = i % OBLK, k = i / OBLK;
        int o = oc * OBLK + o_l;
        w_s[i] = (o < CO) ? ga[w_off + (long)o * KTOT + k] : (u16)0;
    }
    __syncthreads();

    int lane = threadIdx.x & 31, og = threadIdx.x >> 5;
    int pixoff[R], pxg[R];
    bool vld[R];
    #pragma unroll
    for (int r = 0; r < R; ++r) {
        int px = pxc * (32 * R) + lane + r * 32;
        vld[r] = px < NPX;
        int p = vld[r] ? px : 0;
        pxg[r] = p;
        pixoff[r] = (p / OW) * W + (p % OW);
    }
    float acc[R][OPT];
    #pragma unroll
    for (int r = 0; r < R; ++r)
        #pragma unroll
        for (int j = 0; j < OPT; ++j) acc[r][j] = 0.f;

    const u32* wu = (const u32*)w_s;
    for (int c = 0; c < CIN; ++c) {
        #pragma unroll
        for (int ky = 0; ky < KH; ++ky) {
            #pragma unroll
            for (int kx = 0; kx < KW; ++kx) {
                int k = (c * KH + ky) * KW + kx;
                int ub = c * (H * W) + ky * W + kx;
                float a[R];
                #pragma unroll
                for (int r = 0; r < R; ++r) a[r] = us2f(in_s[ub + pixoff[r]]);
                int wb = (k * OBLK + og * OPT) >> 1;
                float wv[OPT];
                #pragma unroll
                for (int jj = 0; jj < OPT / 2; ++jj) {
                    u32 u = wu[wb + jj];
                    wv[2 * jj] = ulo(u); wv[2 * jj + 1] = uhi(u);
                }
                #pragma unroll
                for (int r = 0; r < R; ++r)
                    #pragma unroll
                    for (int j = 0; j < OPT; ++j)
                        acc[r][j] += a[r] * wv[j];
            }
        }
    }
    #pragma unroll
    for (int j = 0; j < OPT; ++j) {
        int o = oc * OBLK + og * OPT + j;
        if (o < CO) {
            float b = us2f(ga[b_off + o]);
            float al = us2f(ga[a_off + o]);
            #pragma unroll
            for (int r = 0; r < R; ++r) if (vld[r]) {
                float v = acc[r][j] + b;
                v = v > 0.f ? v : v * al;
                g_arena[(long)out_off + ((long)n * CO + o) * NPX + pxg[r]] = f2b(v);
            }
        }
    }
}

// ---------------------------------------------------------------------------
// PNet conv1 (3->10) + PReLU + maxpool 2x2 s2.
// ---------------------------------------------------------------------------
__launch_bounds__(256)
__global__ void pnet_c1p_kern(int w_off, int b_off, int a_off, int out_off)
{
    __shared__ u16 patch[3 * 34 * 34];
    __shared__ __align__(16) u16 w_s[27 * 16];
    int n = blockIdx.x, pty = blockIdx.y, ptx = blockIdx.z;
    int cy0 = pty * 32, cx0 = ptx * 32;
    const u16* ga = (const u16*)g_arena;

    for (int i = threadIdx.x; i < 3468; i += 256) {
        int c = i / 1156, rem = i % 1156, py = rem / 34, pxx = rem % 34;
        int iy = cy0 + py, ix = cx0 + pxx;
        u16 v = 0;
        if (iy < 720 && ix < 720)
            v = ga[OFF_IMGS + ((long)(n * 3 + c) * 720 + iy) * 720 + ix];
        patch[i] = v;
    }
    for (int i = threadIdx.x; i < 27 * 16; i += 256) {
        int o = i % 16, k = i / 16;
        w_s[i] = (o < 10) ? ga[w_off + o * 27 + k] : (u16)0;
    }
    __syncthreads();

    int px = threadIdx.x % 16, py = threadIdx.x / 16;
    float acc[2][2][10];
    #pragma unroll
    for (int a = 0; a < 2; ++a)
        #pragma unroll
        for (int b = 0; b < 2; ++b)
            #pragma unroll
            for (int o = 0; o < 10; ++o) acc[a][b][o] = 0.f;

    const uint4* wq = (const uint4*)w_s;
    for (int c = 0; c < 3; ++c) {
        #pragma unroll
        for (int ky = 0; ky < 3; ++ky) {
            #pragma unroll
            for (int kx = 0; kx < 3; ++kx) {
                int k = (c * 3 + ky) * 3 + kx;
                float a[2][2];
                #pragma unroll
                for (int dy = 0; dy < 2; ++dy)
                    #pragma unroll
                    for (int dx = 0; dx < 2; ++dx)
                        a[dy][dx] = us2f(patch[c * 1156 + (2 * py + dy + ky) * 34 + (2 * px + dx + kx)]);
                uint4 q0 = wq[k * 2], q1 = wq[k * 2 + 1];
                float wv[10];
                wv[0] = ulo(q0.x); wv[1] = uhi(q0.x); wv[2] = ulo(q0.y); wv[3] = uhi(q0.y);
                wv[4] = ulo(q0.z); wv[5] = uhi(q0.z); wv[6] = ulo(q0.w); wv[7] = uhi(q0.w);
                wv[8] = ulo(q1.x); wv[9] = uhi(q1.x);
                #pragma unroll
                for (int o = 0; o < 10; ++o)
                    #pragma unroll
                    for (int dy = 0; dy < 2; ++dy)
                        #pragma unroll
                        for (int dx = 0; dx < 2; ++dx)
                            acc[dy][dx][o] += a[dy][dx] * wv[o];
            }
        }
    }
    int pgy = pty * 16 + py, pgx = ptx * 16 + px;
    if (pgy < 359 && pgx < 359) {
        #pragma unroll
        for (int o = 0; o < 10; ++o) {
            float b = us2f(ga[b_off + o]);
            float al = us2f(ga[a_off + o]);
            float m = -1e30f;
            #pragma unroll
            for (int dy = 0; dy < 2; ++dy)
                #pragma unroll
                for (int dx = 0; dx < 2; ++dx) {
                    float v = acc[dy][dx][o] + b;
                    v = v > 0.f ? v : v * al;
                    m = fmaxf(m, v);
                }
            g_arena[(long)out_off + ((long)(n * 10 + o) * 359 + pgy) * 359 + pgx] = f2b(m);
        }
    }
}

// ---------------------------------------------------------------------------
// PNet conv2 (10->16).
// ---------------------------------------------------------------------------
__launch_bounds__(256)
__global__ void pnet_c2_kern(int in_off, int w_off, int b_off, int a_off, int out_off)
{
    __shared__ u16 patch[10 * 34 * 34];
    __shared__ __align__(16) u16 w_s[90 * 16];
    int n = blockIdx.x, ty = blockIdx.y, tx = blockIdx.z;
    int y0 = ty * 32, x0 = tx * 32;
    const u16* ga = (const u16*)g_arena;

    for (int i = threadIdx.x; i < 11560; i += 256) {
        int c = i / 1156, rem = i % 1156, py = rem / 34, pxx = rem % 34;
        int iy = y0 + py, ix = x0 + pxx;
        u16 v = 0;
        if (iy < 359 && ix < 359)
            v = ga[in_off + ((long)(n * 10 + c) * 359 + iy) * 359 + ix];
        patch[i] = v;
    }
    for (int i = threadIdx.x; i < 1440; i += 256) {
        int o = i % 16, k = i / 16;
        w_s[i] = ga[w_off + o * 90 + k];
    }
    __syncthreads();

    int x = threadIdx.x % 32, yg = threadIdx.x / 32;
    float acc[4][16];
    #pragma unroll
    for (int r = 0; r < 4; ++r)
        #pragma unroll
        for (int o = 0; o < 16; ++o) acc[r][o] = 0.f;

    const uint4* wq = (const uint4*)w_s;
    for (int c = 0; c < 10; ++c) {
        #pragma unroll
        for (int ky = 0; ky < 3; ++ky) {
            #pragma unroll
            for (int kx = 0; kx < 3; ++kx) {
                int k = (c * 3 + ky) * 3 + kx;
                float a[4];
                #pragma unroll
                for (int r = 0; r < 4; ++r)
                    a[r] = us2f(patch[c * 1156 + (yg + 8 * r + ky) * 34 + (x + kx)]);
                uint4 q0 = wq[k * 2], q1 = wq[k * 2 + 1];
                float wv[16];
                wv[0]=ulo(q0.x); wv[1]=uhi(q0.x); wv[2]=ulo(q0.y); wv[3]=uhi(q0.y);
                wv[4]=ulo(q0.z); wv[5]=uhi(q0.z); wv[6]=ulo(q0.w); wv[7]=uhi(q0.w);
                wv[8]=ulo(q1.x); wv[9]=uhi(q1.x); wv[10]=ulo(q1.y); wv[11]=uhi(q1.y);
                wv[12]=ulo(q1.z); wv[13]=uhi(q1.z); wv[14]=ulo(q1.w); wv[15]=uhi(q1.w);
                #pragma unroll
                for (int r = 0; r < 4; ++r)
                    #pragma unroll
                    for (int o = 0; o < 16; ++o)
                        acc[r][o] += a[r] * wv[o];
            }
        }
    }
    #pragma unroll
    for (int o = 0; o < 16; ++o) {
        float b = us2f(ga[b_off + o]);
        float al = us2f(ga[a_off + o]);
        #pragma unroll
        for (int r = 0; r < 4; ++r) {
            int gy = y0 + yg + 8 * r, gx = x0 + x;
            if (gy < 357 && gx < 357) {
                float v = acc[r][o] + b;
                v = v > 0.f ? v : v * al;
                g_arena[(long)out_off + ((long)(n * 16 + o) * 357 + gy) * 357 + gx] = f2b(v);
            }
        }
    }
}

// ---------------------------------------------------------------------------
// PNet conv3 (16->32) + PReLU + 1x1 heads + softmax, fused.
// ---------------------------------------------------------------------------
__launch_bounds__(256)
__global__ void pnet_c3h_kern(int in_off, int w3o, int b3o, int a3o,
                              int w41o, int b41o, int w42o, int b42o, void* dout)
{
    __shared__ u16 patch[16 * 10 * 34];
    __shared__ __align__(16) u16 w3s[144 * 32];
    __shared__ float c3s[256 * 33];
    __shared__ float b3f[32], a3f[32], w41f[64], w42f[128], b41f[2], b42f[4];

    int n = blockIdx.x, by = blockIdx.y, tx = blockIdx.z;
    int gy0 = by * 8, gx0 = tx * 32;
    const u16* ga = (const u16*)g_arena;

    for (int i = threadIdx.x; i < 5440; i += 256) {
        int c = i / 340, rem = i % 340, py = rem / 34, pxx = rem % 34;
        int iy = gy0 + py, ix = gx0 + pxx;
        u16 v = 0;
        if (iy < 357 && ix < 357)
            v = ga[in_off + ((long)(n * 16 + c) * 357 + iy) * 357 + ix];
        patch[i] = v;
    }
    for (int i = threadIdx.x; i < 4608; i += 256) {
        int o = i % 32, k = i / 32;
        w3s[i] = ga[w3o + o * 144 + k];
    }
    for (int i = threadIdx.x; i < 32; i += 256) { b3f[i] = us2f(ga[b3o + i]); a3f[i] = us2f(ga[a3o + i]); }
    for (int i = threadIdx.x; i < 64; i += 256) w41f[i] = us2f(ga[w41o + i]);
    for (int i = threadIdx.x; i < 128; i += 256) w42f[i] = us2f(ga[w42o + i]);
    if (threadIdx.x < 2) b41f[threadIdx.x] = us2f(ga[b41o + threadIdx.x]);
    if (threadIdx.x < 4) b42f[threadIdx.x] = us2f(ga[b42o + threadIdx.x]);
    __syncthreads();

    int lane = threadIdx.x & 63, og = threadIdx.x >> 6;
    int pb[4];
    #pragma unroll
    for (int r = 0; r < 4; ++r) {
        int p = lane + 64 * r;
        pb[r] = (p >> 5) * 34 + (p & 31);
    }
    float acc[4][8];
    #pragma unroll
    for (int r = 0; r < 4; ++r)
        #pragma unroll
        for (int j = 0; j < 8; ++j) acc[r][j] = 0.f;

    const uint4* wq = (const uint4*)w3s;
    for (int c = 0; c < 16; ++c) {
        #pragma unroll
        for (int ky = 0; ky < 3; ++ky) {
            #pragma unroll
            for (int kx = 0; kx < 3; ++kx) {
                int k = (c * 3 + ky) * 3 + kx;
                int ub = c * 340 + ky * 34 + kx;
                float a[4];
                #pragma unroll
                for (int r = 0; r < 4; ++r) a[r] = us2f(patch[ub + pb[r]]);
                uint4 q = wq[k * 4 + og];
                float wv[8];
                wv[0]=ulo(q.x); wv[1]=uhi(q.x); wv[2]=ulo(q.y); wv[3]=uhi(q.y);
                wv[4]=ulo(q.z); wv[5]=uhi(q.z); wv[6]=ulo(q.w); wv[7]=uhi(q.w);
                #pragma unroll
                for (int r = 0; r < 4; ++r)
                    #pragma unroll
                    for (int j = 0; j < 8; ++j)
                        acc[r][j] += a[r] * wv[j];
            }
        }
    }
    #pragma unroll
    for (int j = 0; j < 8; ++j) {
        int o = og * 8 + j;
        float b = b3f[o], al = a3f[o];
        #pragma unroll
        for (int r = 0; r < 4; ++r) {
            int p = lane + 64 * r;
            float v = acc[r][j] + b;
            v = v > 0.f ? v : v * al;
            c3s[p * 33 + o] = v;
        }
    }
    __syncthreads();

    int p = threadIdx.x;
    int gy = gy0 + (p >> 5), gx = gx0 + (p & 31);
    if (gy < 355 && gx < 355) {
        int f32 = g_isf32;
        float l0 = b41f[0], l1 = b41f[1];
        float r0 = b42f[0], r1 = b42f[1], r2 = b42f[2], r3 = b42f[3];
        #pragma unroll
        for (int o = 0; o < 32; ++o) {
            float v = c3s[p * 33 + o];
            l0 += v * w41f[o];
            l1 += v * w41f[32 + o];
            r0 += v * w42f[o];
            r1 += v * w42f[32 + o];
            r2 += v * w42f[64 + o];
            r3 += v * w42f[96 + o];
        }
        float mx = fmaxf(l0, l1);
        float e0 = __expf(l0 - mx), e1 = __expf(l1 - mx);
        float inv = 1.f / (e0 + e1);
        const long HW = 355L * 355L;
        long pix = (long)gy * 355 + gx;
        stout(dout, 4032800 + ((long)n * 2 + 0) * HW + pix, e0 * inv, f32);
        stout(dout, 4032800 + ((long)n * 2 + 1) * HW + pix, e1 * inv, f32);
        stout(dout, ((long)n * 4 + 0) * HW + pix, r0, f32);
        stout(dout, ((long)n * 4 + 1) * HW + pix, r1, f32);
        stout(dout, ((long)n * 4 + 2) * HW + pix, r2, f32);
        stout(dout, ((long)n * 4 + 3) * HW + pix, r3, f32);
    }
}

// ---------------------------------------------------------------------------
// MaxPool2d, ceil_mode (OOB taps skipped).
// ---------------------------------------------------------------------------
__global__ void maxpool_kern(int in_off, int out_off,
                             int H, int W, int OH, int OW, int k, int s, int total)
{
    int tid = blockIdx.x * blockDim.x + threadIdx.x;
    if (tid >= total) return;
    int x = tid % OW;
    int t = tid / OW;
    int y = t % OH;
    int nc = t / OH;
    const bf16* ip = g_arena + in_off + (long)nc * H * W;
    int sy = y * s, sx = x * s;
    float m = -1e30f;
    for (int ky = 0; ky < k; ++ky) {
        int iy = sy + ky;
        if (iy >= H) break;
        for (int kx = 0; kx < k; ++kx) {
            int ix = sx + kx;
            if (ix >= W) break;
            m = fmaxf(m, b2f(ip[iy * W + ix]));
        }
    }
    g_arena[(long)out_off + tid] = f2b(m);
}

// ---------------------------------------------------------------------------
// Flatten: torch permute(0,3,2,1).view -> out[n][w*H*C + h*C + c]
// ---------------------------------------------------------------------------
__global__ void flatten_kern(int in_off, int out_off, int C, int H, int W, int total)
{
    int tid = blockIdx.x * blockDim.x + threadIdx.x;
    if (tid >= total) return;
    int CHW = C * H * W;
    int n = tid / CHW;
    int k = tid % CHW;
    int w = k / (H * C);
    int r = k % (H * C);
    int h = r / C;
    int c = r % C;
    g_arena[(long)out_off + tid] = g_arena[in_off + (((long)n * C + c) * H + h) * W + w];
}

// ---------------------------------------------------------------------------
// Dense + bias + PReLU as tiled LDS GEMM. Block = 32 samples x 32 outputs,
// 256 threads = 16x16, each a 2x2 micro-tile; K staged in 64-chunks.
// LDS stride 66: bank = (2*row + k) % 32 -> only free 2-way aliasing.
// Requires K % 64 == 0, N % 32 == 0, J % 32 == 0 (576/1152, 2048/512, 128/256 ok).
// ---------------------------------------------------------------------------
__launch_bounds__(256)
__global__ void dense_tile_kern(int in_off, int w_off, int b_off, int a_off, int out_off,
                                int K, int J)
{
    __shared__ u16 in_s[32 * 66];
    __shared__ u16 w_s[32 * 66];
    int n0 = blockIdx.x * 32, j0 = blockIdx.y * 32;
    const u16* ga = (const u16*)g_arena;
    const u16* fin = ga + in_off;
    const u16* wts = ga + w_off;
    int sy = threadIdx.x >> 4, sx = threadIdx.x & 15;

    float acc00 = 0.f, acc01 = 0.f, acc10 = 0.f, acc11 = 0.f;

    for (int kc = 0; kc < K; kc += 64) {
        #pragma unroll
        for (int it = 0; it < 4; ++it) {
            int i = threadIdx.x + it * 256;          // 0..1023
            int row = i >> 5, c2 = i & 31;
            u32 v = *(const u32*)(fin + (long)(n0 + row) * K + kc + c2 * 2);
            *(u32*)&in_s[row * 66 + c2 * 2] = v;
            u32 wv = *(const u32*)(wts + (long)(j0 + row) * K + kc + c2 * 2);
            *(u32*)&w_s[row * 66 + c2 * 2] = wv;
        }
        __syncthreads();
        #pragma unroll
        for (int kk = 0; kk < 64; ++kk) {
            float a0 = us2f(in_s[(2 * sy) * 66 + kk]);
            float a1 = us2f(in_s[(2 * sy + 1) * 66 + kk]);
            float b0 = us2f(w_s[(2 * sx) * 66 + kk]);
            float b1 = us2f(w_s[(2 * sx + 1) * 66 + kk]);
            acc00 += a0 * b0; acc01 += a0 * b1;
            acc10 += a1 * b0; acc11 += a1 * b1;
        }
        __syncthreads();
    }

    float accs[2][2] = {{acc00, acc01}, {acc10, acc11}};
    #pragma unroll
    for (int jj = 0; jj < 2; ++jj) {
        int j = j0 + 2 * sx + jj;
        float b = us2f(ga[b_off + j]);
        float al = us2f(ga[a_off + j]);
        #pragma unroll
        for (int ss = 0; ss < 2; ++ss) {
            int n = n0 + 2 * sy + ss;
            float v = accs[ss][jj] + b;
            v = v > 0.f ? v : v * al;
            g_arena[(long)out_off + (long)n * J + j] = f2b(v);
        }
    }
}

// ---------------------------------------------------------------------------
// Heads, wave-per-sample: 64 lanes partition K; butterfly shuffle reduction.
// ---------------------------------------------------------------------------
template<int K, int J1, int J2>
__launch_bounds__(256)
__global__ void heads_wave_kern(int fc_off, int wSo, int bSo, int w1o, int b1o,
                                int w2o, int b2o, void* dout,
                                long outS_off, long out1_off, long out2_off, int N)
{
    constexpr int KPL = K / 64;
    constexpr int NACC = 2 + J1 + J2;
    int wave = (blockIdx.x * blockDim.x + threadIdx.x) >> 6;
    int lane = threadIdx.x & 63;
    if (wave >= N) return;
    const u16* ga = (const u16*)g_arena;
    const u16* f  = ga + fc_off + (long)wave * K;
    const u16* wS = ga + wSo;
    const u16* w1 = ga + w1o;
    const u16* w2 = ga + w2o;

    float acc[NACC];
    #pragma unroll
    for (int j = 0; j < NACC; ++j) acc[j] = 0.f;

    #pragma unroll
    for (int kk = 0; kk < KPL; ++kk) {
        int k = lane + kk * 64;
        float fv = us2f(f[k]);
        acc[0] += fv * us2f(wS[k]);
        acc[1] += fv * us2f(wS[K + k]);
        #pragma unroll
        for (int j = 0; j < J1; ++j)
            acc[2 + j] += fv * us2f(w1[j * K + k]);
        #pragma unroll
        for (int j = 0; j < J2; ++j)
            acc[2 + J1 + j] += fv * us2f(w2[j * K + k]);
    }
    #pragma unroll
    for (int j = 0; j < NACC; ++j)
        #pragma unroll
        for (int off = 32; off > 0; off >>= 1)
            acc[j] += __shfl_xor(acc[j], off, 64);

    if (lane == 0) {
        int f32 = g_isf32;
        float l0 = acc[0] + us2f(ga[bSo + 0]);
        float l1 = acc[1] + us2f(ga[bSo + 1]);
        float m = fmaxf(l0, l1);
        float e0 = __expf(l0 - m), e1 = __expf(l1 - m);
        float inv = 1.f / (e0 + e1);
        stout(dout, outS_off + (long)wave * 2 + 0, e0 * inv, f32);
        stout(dout, outS_off + (long)wave * 2 + 1, e1 * inv, f32);
        #pragma unroll
        for (int j = 0; j < J1; ++j)
            stout(dout, out1_off + (long)wave * J1 + j, acc[2 + j] + us2f(ga[b1o + j]), f32);
        #pragma unroll
        for (int j = 0; j < J2; ++j)
            stout(dout, out2_off + (long)wave * J2 + j, acc[2 + J1 + j] + us2f(ga[b2o + j]), f32);
    }
}

static inline dim3 g1(int total) { return dim3((unsigned)((total + 255) / 256)); }

extern "C" void kernel_launch(void* const* d_in, const int* in_sizes, int n_in,
                              void* d_out, int out_size, void* d_ws, size_t ws_size,
                              hipStream_t stream)
{
    int woff[53];
    int acc = OFF_WTS;
    int mx = 0;
    for (int i = 3; i < 53; ++i) { woff[i] = acc; acc += in_sizes[i]; if (in_sizes[i] > mx) mx = in_sizes[i]; }

    detect_kern<<<1, 64, 0, stream>>>(d_in[0]);
    convert_kern<<<g1(12441600), 256, 0, stream>>>(d_in[0], OFF_IMGS, 12441600);
    convert_kern<<<g1(3538944), 256, 0, stream>>>(d_in[1], OFF_C24, 3538944);
    convert_kern<<<g1(3538944), 256, 0, stream>>>(d_in[2], OFF_C48, 3538944);
    CvtTab tab;
    for (int i = 3; i < 53; ++i) tab.e[i - 3] = CvtEnt{ d_in[i], woff[i], in_sizes[i] };
    convert_many_kern<<<dim3((unsigned)((mx + 255) / 256), 50), 256, 0, stream>>>(tab);

    // ================= PNet =================
    pnet_c1p_kern<<<dim3(8, 23, 23), 256, 0, stream>>>(woff[3], woff[4], woff[5], OFF_A);
    pnet_c2_kern<<<dim3(8, 12, 12), 256, 0, stream>>>(OFF_A, woff[6], woff[7], woff[8], OFF_B);
    pnet_c3h_kern<<<dim3(8, 45, 12), 256, 0, stream>>>(OFF_B,
        woff[9], woff[10], woff[11], woff[12], woff[13], woff[14], woff[15], d_out);

    // ================= RNet =================
    conv_a_kern<3,3,3,24,24,22,22,28,32,4><<<dim3(2048, 4, 1), 256, 0, stream>>>(
        OFF_C24, woff[16], woff[17], woff[18], OFF_A);
    maxpool_kern<<<g1(6938624), 256, 0, stream>>>(OFF_A, OFF_B, 22, 22, 11, 11, 3, 2, 6938624);
    conv_a_kern<28,3,3,11,11,9,9,48,48,3><<<dim3(2048, 1, 1), 256, 0, stream>>>(
        OFF_B, woff[19], woff[20], woff[21], OFF_A);
    maxpool_kern<<<g1(1572864), 256, 0, stream>>>(OFF_A, OFF_B, 9, 9, 4, 4, 3, 2, 1572864);
    conv_a_kern<48,2,2,4,4,3,3,64,64,1><<<dim3(2048, 1, 1), 256, 0, stream>>>(
        OFF_B, woff[22], woff[23], woff[24], OFF_A);
    flatten_kern<<<g1(1179648), 256, 0, stream>>>(OFF_A, OFF_B, 64, 3, 3, 1179648);
    dense_tile_kern<<<dim3(64, 4), 256, 0, stream>>>(OFF_B, woff[25], woff[26], woff[27], OFF_A,
        576, 128);
    heads_wave_kern<128,4,0><<<dim3(512), 256, 0, stream>>>(OFF_A,
        woff[28], woff[29], woff[30], woff[31], 0, 0,
        d_out, 6057392L, 6049200L, 0L, 2048);

    // ================= ONet =================
    conv_a_kern<3,3,3,48,48,46,46,32,32,4><<<dim3(512, 17, 1), 256, 0, stream>>>(
        OFF_C48, woff[32], woff[33], woff[34], OFF_A);
    maxpool_kern<<<g1(8667136), 256, 0, stream>>>(OFF_A, OFF_B, 46, 46, 23, 23, 3, 2, 8667136);
    conv_a_kern<32,3,3,23,23,21,21,64,64,4><<<dim3(512, 4, 1), 256, 0, stream>>>(
        OFF_B, woff[35], woff[36], woff[37], OFF_A);
    maxpool_kern<<<g1(3276800), 256, 0, stream>>>(OFF_A, OFF_B, 21, 21, 10, 10, 3, 2, 3276800);
    conv_a_kern<64,3,3,10,10,8,8,64,32,2><<<dim3(512, 1, 2), 256, 0, stream>>>(
        OFF_B, woff[38], woff[39], woff[40], OFF_A);
    maxpool_kern<<<g1(524288), 256, 0, stream>>>(OFF_A, OFF_B, 8, 8, 4, 4, 2, 2, 524288);
    conv_a_kern<64,2,2,4,4,3,3,128,64,1><<<dim3(512, 1, 2), 256, 0, stream>>>(
        OFF_B, woff[41], woff[42], woff[43], OFF_A);
    flatten_kern<<<g1(589824), 256, 0, stream>>>(OFF_A, OFF_B, 128, 3, 3, 589824);
    dense_tile_kern<<<dim3(16, 8), 256, 0, stream>>>(OFF_B, woff[44], woff[45], woff[46], OFF_A,
        1152, 256);
    heads_wave_kern<256,4,10><<<dim3(128), 256, 0, stream>>>(OFF_A,
        woff[47], woff[48], woff[49], woff[50], woff[51], woff[52],
        d_out, 6068656L, 6061488L, 6063536L, 512);
}